// Round 7
// baseline (1871.992 us; speedup 1.0000x reference)
//
#include <hip/hip_runtime.h>
#include <hip/hip_bf16.h>
#include <stdint.h>

#define BB 256
#define CC 1024
#define NP 25
#define EPS 1e-5f

typedef __attribute__((ext_vector_type(8))) short bf16x8;
typedef __attribute__((ext_vector_type(4))) float f32x4;
typedef unsigned int u32;

#define MFMA16(A, B, C) __builtin_amdgcn_mfma_f32_16x16x32_bf16(A, B, C, 0, 0, 0)

// async global->LDS, 16B per lane; LDS dest = wave-uniform base + lane*16
__device__ __forceinline__ void gload16(const u32* g, u32* l)
{
  __builtin_amdgcn_global_load_lds(
      (const __attribute__((address_space(1))) u32*)g,
      (__attribute__((address_space(3))) u32*)l, 16, 0, 0);
}

// ---------------------------------------------------------------- utils

__device__ __forceinline__ void head_entry(int j, int* pp, int* ww)
{
  int cnt = 0;
  for (int y1 = 0; y1 < 5; y1++)
    for (int x1 = 0; x1 < 5; x1++) {
      int p = y1 * 5 + x1;
      int y2 = y1 + 2, x2 = x1 + 2;
      if (y2 == 2 || y2 == 3)
        for (int s = 0; s < 3; s++) { if (y2 + s + 1 > 6) break; if (cnt == j) { *pp = p; *ww = 0 + s; return; } cnt++; }
      if (y1 == 3 || y1 == 4)
        for (int s = 0; s < 3; s++) { if (y1 - (s + 1) < 0) break; if (cnt == j) { *pp = p; *ww = 3 + s; return; } cnt++; }
      if (x2 == 2 || x2 == 3)
        for (int s = 0; s < 3; s++) { if (x2 + s + 1 > 6) break; if (cnt == j) { *pp = p; *ww = 6 + s; return; } cnt++; }
      if (x1 == 3 || x1 == 4)
        for (int s = 0; s < 3; s++) { if (x1 - (s + 1) < 0) break; if (cnt == j) { *pp = p; *ww = 9 + s; return; } cnt++; }
    }
}

// split fp32 -> hi bf16 (truncate) + lo bf16 (remainder); pack pairs into u32
__device__ __forceinline__ void split_f4(float4 f, uint2& h, uint2& l)
{
  u32 ux = __float_as_uint(f.x), uy = __float_as_uint(f.y);
  u32 uz = __float_as_uint(f.z), uw = __float_as_uint(f.w);
  h.x = (ux >> 16) | (uy & 0xFFFF0000u);
  h.y = (uz >> 16) | (uw & 0xFFFF0000u);
  float lx = f.x - __uint_as_float(ux & 0xFFFF0000u);
  float ly = f.y - __uint_as_float(uy & 0xFFFF0000u);
  float lz = f.z - __uint_as_float(uz & 0xFFFF0000u);
  float lw = f.w - __uint_as_float(uw & 0xFFFF0000u);
  l.x = (__float_as_uint(lx) >> 16) | (__float_as_uint(ly) & 0xFFFF0000u);
  l.y = (__float_as_uint(lz) >> 16) | (__float_as_uint(lw) & 0xFFFF0000u);
}

// ------------------------------------------------- layer-1 stats from x

__global__ void k_xsums(const float* __restrict__ x, float* __restrict__ xs1,
                        float* __restrict__ xs2)
{
  int pos = blockIdx.x * 256 + threadIdx.x;   // < 50176
  float s1 = 0.f, s2 = 0.f;
  for (int b = 0; b < BB; b++) {
    float v = x[(size_t)b * 50176 + pos];
    s1 += v; s2 = fmaf(v, v, s2);
  }
  xs1[pos] = s1; xs2[pos] = s2;
}

__global__ void k_stats1(const float* __restrict__ xs1, const float* __restrict__ xs2,
                         const float* __restrict__ gam, const float* __restrict__ bet,
                         float* __restrict__ ssc, float* __restrict__ ssh)
{
  int p = blockIdx.x;
  int c = blockIdx.y * 256 + threadIdx.x;
  int y1 = p / 5, x1 = p % 5;
  float s1 = 0.f, s2 = 0.f;
  for (int dy = 0; dy < 3; dy++)
    for (int dx = 0; dx < 3; dx++) {
      int pos = c * 49 + (y1 + dy) * 7 + (x1 + dx);
      s1 += xs1[pos]; s2 += xs2[pos];
    }
  const float inv = 1.0f / 2304.0f;
  float mean = s1 * inv;
  float var  = s2 * inv - mean * mean;
  float rs   = rsqrtf(var + EPS);
  float sc   = rs * gam[c];
  ssc[(size_t)p * CC + c] = sc;
  ssh[(size_t)p * CC + c] = bet[c] - mean * sc;
}

// ------------------------- one-time x transpose: x[b][c][yx] -> xt[b][yx][c]

__global__ void k_transpose(const float* __restrict__ x, float* __restrict__ xt)
{
  __shared__ float tile[128][51];
  int b = blockIdx.x, cg = blockIdx.y;
  const float* src = x + (size_t)b * 50176 + (size_t)cg * 128 * 49;
  for (int idx = threadIdx.x; idx < 6272; idx += 256)
    tile[idx / 49][idx % 49] = src[idx];
  __syncthreads();
  float* dst = xt + (size_t)b * 49 * 1024 + cg * 128;
  for (int pp = 0; pp < 50; pp += 2) {
    int p = pp + (threadIdx.x >> 7);
    int i = threadIdx.x & 127;
    if (p < 49) dst[(size_t)p * 1024 + i] = tile[i][p];
  }
}

// -------------- fallback patch gather + BN1 affine + relu (small-ws tier)

__global__ void k_gather(const float* __restrict__ x, const float* __restrict__ ssc,
                         const float* __restrict__ ssh, float* __restrict__ out,
                         int pbase)
{
  int tid = threadIdx.x;
  int r0 = blockIdx.x * 16;
  for (int rr = 0; rr < 16; rr++) {
    int row = r0 + rr;
    int pl = row / 2304;
    int b  = (row / 9) & 255;
    int yx = row % 9;
    int pg = pbase + pl;
    int pos = (pg / 5 + yx / 3) * 7 + (pg % 5) + (yx % 3);
    const float* xb  = x + (size_t)b * CC * 49 + pos;
    const float* scp = ssc + (size_t)pg * CC;
    const float* shp = ssh + (size_t)pg * CC;
    float* op = out + (size_t)row * CC;
    #pragma unroll
    for (int q = 0; q < 4; q++) {
      int c = q * 256 + tid;
      float v = xb[(size_t)c * 49];
      op[c] = fmaxf(fmaf(v, scp[c], shp[c]), 0.f);
    }
  }
}

// ---------- weight/ctx pre-split into gload-ready interleaved hi/lo layout
// out row = 1024 u32: [slab 0..31][ 16 u32 hi pairs | 16 u32 lo pairs ]

__global__ void k_wsplit(const float* __restrict__ w, u32* __restrict__ dst, int total)
{
  int g = blockIdx.x * 256 + threadIdx.x;
  if (g >= total) return;
  int row = g >> 10;
  int rem = g & 1023;
  int slab = rem >> 5, j = rem & 31;
  int lo = j >> 4, jj = j & 15;
  const float* src = w + ((size_t)row << 10) + slab * 32 + 2 * jj;
  float f0 = src[0], f1 = src[1];
  u32 u0 = __float_as_uint(f0), u1 = __float_as_uint(f1);
  u32 v;
  if (lo == 0) {
    v = (u0 >> 16) | (u1 & 0xFFFF0000u);
  } else {
    float l0 = f0 - __uint_as_float(u0 & 0xFFFF0000u);
    float l1 = f1 - __uint_as_float(u1 & 0xFFFF0000u);
    v = (__float_as_uint(l0) >> 16) | (__float_as_uint(l1) & 0xFFFF0000u);
  }
  dst[g] = v;
}

// -------- BN3 stats-final (from partB) + affine + relu + 3x3 mean pooling

__global__ void k_pool(const float* __restrict__ h, const float* __restrict__ part,
                       const float* __restrict__ gam, const float* __restrict__ bet,
                       float* __restrict__ apool, int pbase)
{
  int row = blockIdx.x;                 // pl*256 + b
  int pl = row >> 8;
  int c = threadIdx.x * 4;
  // stats-final for 4 channels (same summation order as old k_statsfin)
  float s1[4] = {0.f, 0.f, 0.f, 0.f}, s2[4] = {0.f, 0.f, 0.f, 0.f};
  for (int mb = 0; mb < 18; mb++) {
    const float* pp = part + ((size_t)(pl * 18 + mb) * CC + c) * 2;
    #pragma unroll
    for (int e = 0; e < 4; e++) { s1[e] += pp[2 * e]; s2[e] += pp[2 * e + 1]; }
  }
  float4 sc, sh;
  {
    const float inv = 1.0f / 2304.0f;
    float scv[4], shv[4];
    #pragma unroll
    for (int e = 0; e < 4; e++) {
      float mean = s1[e] * inv;
      float var  = s2[e] * inv - mean * mean;
      float rs   = rsqrtf(var + EPS);
      float g    = rs * gam[c + e];
      scv[e] = g; shv[e] = bet[c + e] - mean * g;
    }
    sc = make_float4(scv[0], scv[1], scv[2], scv[3]);
    sh = make_float4(shv[0], shv[1], shv[2], shv[3]);
  }
  const float* hp = h + (size_t)row * 9 * CC + c;
  float4 s = {0.f, 0.f, 0.f, 0.f};
  #pragma unroll
  for (int yx = 0; yx < 9; yx++) {
    float4 v = *(const float4*)(hp + (size_t)yx * CC);
    s.x += fmaxf(fmaf(v.x, sc.x, sh.x), 0.f);
    s.y += fmaxf(fmaf(v.y, sc.y, sh.y), 0.f);
    s.z += fmaxf(fmaf(v.z, sc.z, sh.z), 0.f);
    s.w += fmaxf(fmaf(v.w, sc.w, sh.w), 0.f);
  }
  const float inv9 = 1.0f / 9.0f;
  float4 o = { s.x * inv9, s.y * inv9, s.z * inv9, s.w * inv9 };
  *(float4*)(apool + (size_t)row * CC + c) = o;
}

// ------------------------------------------------------------ MFMA GEMM core
// C[m][n] = sum_k f(A[m][k]) * B[n][k] + bias[n]
// split-bf16: acc += ah*bh + al*bh + ah*bl  (fp32 MFMA accumulate)
// LDS layout per 128-row tile: row*32 u32, granule g (16B) at phys g^(row&7).
// MODE: 0 = A fp32 reg-staged, identity rows
//       1 = A fp32 reg-staged + BN affine/relu with stats finalized IN-BLOCK
//           from partIn (18 float2 rows per patch) into LDS
//       2 = A fp32 reg-staged + BN1 affine/relu (global ssc/ssh), xt row-map
//       3 = A pre-split, gload (heads)
// B always pre-split planes via global_load_lds.
// STATS: emit per-block column sum/sumsq to partOut[mb][col][2].

template<int MODE, bool STATS>
__device__ __forceinline__ void mg_body(
    const float* __restrict__ Af, const u32* __restrict__ Agl,
    const u32* __restrict__ Bp, const float* __restrict__ bias,
    float* __restrict__ Cmat, const float* __restrict__ ssc,
    const float* __restrict__ ssh, const float* __restrict__ gam,
    const float* __restrict__ bet, const float* __restrict__ partIn,
    int pbase, int m0, int n0,
    float* __restrict__ partOut, int mb)
{
  __shared__ u32 sA[2][4096];
  __shared__ u32 sB[2][4096];
  __shared__ float sr1[4][64];
  __shared__ float sr2[4][64];

  const int t = threadIdx.x;
  const int l = t & 63, wv = t >> 6;
  const int lr = l & 15, lk = l >> 4;
  const int wm = (wv >> 1) * 64, wn = (wv & 1) * 64;

  // fragment read offsets (u32) with granule XOR swizzle
  int fAh[4], fAl[4], fBh[4], fBl[4];
  #pragma unroll
  for (int i = 0; i < 4; i++) {
    int Ra = wm + i * 16 + lr;
    int Rb = wn + i * 16 + lr;
    fAh[i] = Ra * 32 + ((lk ^ (Ra & 7)) << 2);
    fAl[i] = Ra * 32 + (((4 + lk) ^ (Ra & 7)) << 2);
    fBh[i] = Rb * 32 + ((lk ^ (Rb & 7)) << 2);
    fBl[i] = Rb * 32 + (((4 + lk) ^ (Rb & 7)) << 2);
  }

  // gload addressing: wave covers rows wv*32..wv*32+31 in 4 chunks of 8 rows
  int growq[4], ggq[4];
  #pragma unroll
  for (int q = 0; q < 4; q++) {
    int rr = wv * 32 + q * 8 + (l >> 3);
    growq[q] = rr;
    ggq[q] = (((l & 7) ^ (rr & 7)) << 2);
  }
  const u32* Brow = Bp + (size_t)n0 * 1024;
  const u32* Agr  = (MODE == 3) ? (Agl + (size_t)m0 * 1024) : nullptr;

  // reg-staging setup (MODE<3): thread = (row sr, 16-float half sh_)
  const int sr = t >> 1, sh_ = t & 1;
  const float *arow = nullptr, *scp = nullptr, *shp = nullptr;
  int wA[4] = {0, 0, 0, 0};

  // MODE 1: finalize BN stats in-block into LDS (bit-identical order to the
  // old k_statsfin: mb = 0..17 ascending)
  __shared__ float sSC[(MODE == 1) ? 1024 : 1];
  __shared__ float sSH[(MODE == 1) ? 1024 : 1];
  if (MODE == 1) {
    int pl = m0 / 2304;
    for (int c = t; c < 1024; c += 256) {
      float s1 = 0.f, s2 = 0.f;
      for (int mb2 = 0; mb2 < 18; mb2++) {
        const float* pp = partIn + ((size_t)(pl * 18 + mb2) * CC + c) * 2;
        s1 += pp[0]; s2 += pp[1];
      }
      const float inv = 1.0f / 2304.0f;
      float mean = s1 * inv;
      float var  = s2 * inv - mean * mean;
      float rs   = rsqrtf(var + EPS);
      float g    = rs * gam[c];
      sSC[c] = g;
      sSH[c] = bet[c] - mean * g;
    }
    __syncthreads();
  }

  if (MODE < 3) {
    wA[0] = sr * 32 + (((2 * sh_)     ^ (sr & 7)) << 2);
    wA[1] = sr * 32 + (((2 * sh_ + 1) ^ (sr & 7)) << 2);
    wA[2] = sr * 32 + (((4 + 2 * sh_) ^ (sr & 7)) << 2);
    wA[3] = sr * 32 + (((5 + 2 * sh_) ^ (sr & 7)) << 2);
    if (MODE == 2) {
      int pl = m0 / 2304, pg = pbase + pl;
      int q = m0 + sr - pl * 2304;
      int b = q / 9, yx = q % 9;
      int pos = (pg / 5 + yx / 3) * 7 + (pg % 5) + (yx % 3);
      arow = Af + ((size_t)b * 49 + pos) * CC + sh_ * 16;
      scp = ssc + (size_t)pg * CC + sh_ * 16;
      shp = ssh + (size_t)pg * CC + sh_ * 16;
    } else {
      arow = Af + (size_t)(m0 + sr) * CC + sh_ * 16;
      if (MODE == 1) {
        scp = &sSC[sh_ * 16];
        shp = &sSH[sh_ * 16];
      }
    }
  }

  f32x4 acc[4][4];
  #pragma unroll
  for (int i = 0; i < 4; i++)
    #pragma unroll
    for (int j = 0; j < 4; j++) { f32x4 z = {0.f, 0.f, 0.f, 0.f}; acc[i][j] = z; }

  float4 areg[4];

  // prologue: stage slab 0
  {
    #pragma unroll
    for (int q = 0; q < 4; q++)
      gload16(Brow + (size_t)growq[q] * 1024 + ggq[q],
              &sB[0][(wv * 32 + q * 8) * 32]);
    if (MODE == 3) {
      #pragma unroll
      for (int q = 0; q < 4; q++)
        gload16(Agr + (size_t)growq[q] * 1024 + ggq[q],
                &sA[0][(wv * 32 + q * 8) * 32]);
    } else {
      areg[0] = *(const float4*)(arow + 0);
      areg[1] = *(const float4*)(arow + 4);
      areg[2] = *(const float4*)(arow + 8);
      areg[3] = *(const float4*)(arow + 12);
      if (MODE == 1 || MODE == 2) {
        #pragma unroll
        for (int v = 0; v < 4; v++) {
          float4 s = *(const float4*)(scp + v * 4);
          float4 h = *(const float4*)(shp + v * 4);
          areg[v].x = fmaxf(fmaf(areg[v].x, s.x, h.x), 0.f);
          areg[v].y = fmaxf(fmaf(areg[v].y, s.y, h.y), 0.f);
          areg[v].z = fmaxf(fmaf(areg[v].z, s.z, h.z), 0.f);
          areg[v].w = fmaxf(fmaf(areg[v].w, s.w, h.w), 0.f);
        }
      }
      uint2 h0, l0, h1, l1, h2, l2, h3, l3;
      split_f4(areg[0], h0, l0); split_f4(areg[1], h1, l1);
      split_f4(areg[2], h2, l2); split_f4(areg[3], h3, l3);
      *(uint4*)&sA[0][wA[0]] = make_uint4(h0.x, h0.y, h1.x, h1.y);
      *(uint4*)&sA[0][wA[1]] = make_uint4(h2.x, h2.y, h3.x, h3.y);
      *(uint4*)&sA[0][wA[2]] = make_uint4(l0.x, l0.y, l1.x, l1.y);
      *(uint4*)&sA[0][wA[3]] = make_uint4(l2.x, l2.y, l3.x, l3.y);
    }
  }
  __syncthreads();

  #pragma unroll 1
  for (int it = 0; it < 32; ++it) {
    const int cur = it & 1, nxt = cur ^ 1;
    const int kk2 = (it + 1) << 5;
    const bool pf = (it < 31);
    if (pf) {
      int so = kk2;
      #pragma unroll
      for (int q = 0; q < 4; q++)
        gload16(Brow + (size_t)growq[q] * 1024 + so + ggq[q],
                &sB[nxt][(wv * 32 + q * 8) * 32]);
      if (MODE == 3) {
        #pragma unroll
        for (int q = 0; q < 4; q++)
          gload16(Agr + (size_t)growq[q] * 1024 + so + ggq[q],
                  &sA[nxt][(wv * 32 + q * 8) * 32]);
      } else {
        areg[0] = *(const float4*)(arow + kk2);
        areg[1] = *(const float4*)(arow + kk2 + 4);
        areg[2] = *(const float4*)(arow + kk2 + 8);
        areg[3] = *(const float4*)(arow + kk2 + 12);
      }
    }
    // compute on cur
    bf16x8 Ah[4], Al_[4], Bh[4], Bl[4];
    #pragma unroll
    for (int i = 0; i < 4; i++) {
      Ah[i]  = *(const bf16x8*)&sA[cur][fAh[i]];
      Al_[i] = *(const bf16x8*)&sA[cur][fAl[i]];
      Bh[i]  = *(const bf16x8*)&sB[cur][fBh[i]];
      Bl[i]  = *(const bf16x8*)&sB[cur][fBl[i]];
    }
    #pragma unroll
    for (int i = 0; i < 4; i++)
      #pragma unroll
      for (int j = 0; j < 4; j++) {
        acc[i][j] = MFMA16(Ah[i],  Bh[j], acc[i][j]);
        acc[i][j] = MFMA16(Al_[i], Bh[j], acc[i][j]);
        acc[i][j] = MFMA16(Ah[i],  Bl[j], acc[i][j]);
      }
    if (pf && MODE < 3) {
      if (MODE == 1 || MODE == 2) {
        #pragma unroll
        for (int v = 0; v < 4; v++) {
          float4 s = *(const float4*)(scp + kk2 + v * 4);
          float4 h = *(const float4*)(shp + kk2 + v * 4);
          areg[v].x = fmaxf(fmaf(areg[v].x, s.x, h.x), 0.f);
          areg[v].y = fmaxf(fmaf(areg[v].y, s.y, h.y), 0.f);
          areg[v].z = fmaxf(fmaf(areg[v].z, s.z, h.z), 0.f);
          areg[v].w = fmaxf(fmaf(areg[v].w, s.w, h.w), 0.f);
        }
      }
      uint2 h0, l0, h1, l1, h2, l2, h3, l3;
      split_f4(areg[0], h0, l0); split_f4(areg[1], h1, l1);
      split_f4(areg[2], h2, l2); split_f4(areg[3], h3, l3);
      *(uint4*)&sA[nxt][wA[0]] = make_uint4(h0.x, h0.y, h1.x, h1.y);
      *(uint4*)&sA[nxt][wA[1]] = make_uint4(h2.x, h2.y, h3.x, h3.y);
      *(uint4*)&sA[nxt][wA[2]] = make_uint4(l0.x, l0.y, l1.x, l1.y);
      *(uint4*)&sA[nxt][wA[3]] = make_uint4(l2.x, l2.y, l3.x, l3.y);
    }
    __syncthreads();
  }

  // epilogue: D row = lk*4 + reg, col = lr [m89 layout]; optional col stats
  float st1[4], st2[4];
  #pragma unroll
  for (int j = 0; j < 4; j++) { st1[j] = 0.f; st2[j] = 0.f; }
  #pragma unroll
  for (int j = 0; j < 4; j++) {
    int ocol = n0 + wn + j * 16 + lr;
    float bj = bias[ocol];
    #pragma unroll
    for (int i = 0; i < 4; i++) {
      int orow = m0 + wm + i * 16 + lk * 4;
      float* cp = Cmat + (size_t)orow * CC + ocol;
      #pragma unroll
      for (int reg = 0; reg < 4; reg++) {
        float v = acc[i][j][reg] + bj;
        cp[(size_t)reg * CC] = v;
        if (STATS) { st1[j] += v; st2[j] = fmaf(v, v, st2[j]); }
      }
    }
  }
  if (STATS) {
    #pragma unroll
    for (int j = 0; j < 4; j++) {
      st1[j] += __shfl_xor(st1[j], 16, 64);
      st1[j] += __shfl_xor(st1[j], 32, 64);
      st2[j] += __shfl_xor(st2[j], 16, 64);
      st2[j] += __shfl_xor(st2[j], 32, 64);
    }
    if (lk == 0) {
      #pragma unroll
      for (int j = 0; j < 4; j++) {
        sr1[wv][j * 16 + lr] = st1[j];
        sr2[wv][j * 16 + lr] = st2[j];
      }
    }
    __syncthreads();
    if (t < 128) {
      int ch = t >> 6, c6 = t & 63;
      float a1 = sr1[ch][c6] + sr1[ch + 2][c6];
      float a2 = sr2[ch][c6] + sr2[ch + 2][c6];
      float2 o = { a1, a2 };
      *(float2*)(partOut + ((size_t)mb * CC + n0 + t) * 2) = o;
    }
  }
}

template<int MODE, bool STATS>
__global__ __launch_bounds__(256, 2)
void k_mg(const float* __restrict__ Af, const u32* __restrict__ Bp,
          const float* __restrict__ bias, float* __restrict__ Cmat,
          const float* __restrict__ ssc, const float* __restrict__ ssh,
          const float* __restrict__ gam, const float* __restrict__ bet,
          const float* __restrict__ partIn, int pbase,
          float* __restrict__ partOut)
{
  mg_body<MODE, STATS>(Af, nullptr, Bp, bias, Cmat, ssc, ssh, gam, bet,
                       partIn, pbase, blockIdx.x * 128, blockIdx.y * 128,
                       partOut, blockIdx.x);
}

template<int MODE>
__global__ __launch_bounds__(256, 2)
void k_heads(const float* __restrict__ ctx, const u32* __restrict__ ctxp,
             const u32* __restrict__ wplh, const float* __restrict__ lb,
             float* __restrict__ out)
{
  int p, w;
  head_entry(blockIdx.y, &p, &w);
  mg_body<MODE, false>(ctx + (size_t)p * BB * CC,
                       ctxp ? ctxp + (size_t)p * BB * 1024 : nullptr,
                       wplh + (size_t)w * 1048576,
                       lb + (size_t)w * CC,
                       out + (size_t)blockIdx.y * BB * CC,
                       nullptr, nullptr, nullptr, nullptr, nullptr, 0,
                       (blockIdx.x >> 3) * 128, (blockIdx.x & 7) * 128,
                       nullptr, 0);
}

// ---------------------------------------------------------------- launch

extern "C" void kernel_launch(void* const* d_in, const int* in_sizes, int n_in,
                              void* d_out, int out_size, void* d_ws, size_t ws_size,
                              hipStream_t stream)
{
  const float* x   = (const float*)d_in[0];
  const float* bng = (const float*)d_in[1];
  const float* bnb = (const float*)d_in[2];
  const float* cw  = (const float*)d_in[3];
  const float* cb  = (const float*)d_in[4];
  const float* lw  = (const float*)d_in[5];
  const float* lb  = (const float*)d_in[6];
  float* out = (float*)d_out;
  float* ws  = (float*)d_ws;

  const size_t W = ws_size / 4;           // 4-byte words
  const size_t SZ_WPL = 15ull * 1048576;
  const size_t SZ_XT  = 256ull * 49 * 1024;
  const size_t SZ_G   = 2304ull * 1024;
  const size_t SZ_CTX = 6400ull * 1024;
  const size_t SZ_XS  = 50176;
  const size_t SZ_SS  = 25ull * 1024;

  auto need = [&](int PC, bool xt, bool cp) -> size_t {
    size_t Mc = (size_t)PC * 2304;
    return SZ_WPL + (xt ? SZ_XT : SZ_G) + 2 * Mc * 1024
         + (size_t)PC * 256 * 1024 + SZ_CTX + 2 * SZ_XS + 2 * SZ_SS
         + 2 * (Mc / 128) * 1024 * 2 + (cp ? SZ_CTX : 0);
  };
  int PC; bool useXT, useCP;
  if      (W >= need(25, true, true)) { PC = 25; useXT = true;  useCP = true;  }
  else if (W >= need(5, true, true))  { PC = 5;  useXT = true;  useCP = true;  }
  else if (W >= need(5, true, false)) { PC = 5;  useXT = true;  useCP = false; }
  else if (W >= need(1, true, false)) { PC = 1;  useXT = true;  useCP = false; }
  else                                { PC = 1;  useXT = false; useCP = false; }

  const int NCH = NP / PC;
  const size_t Mc = (size_t)PC * 2304;

  u32*   wpl    = (u32*)ws;
  float* xtg    = (float*)(wpl + SZ_WPL);       // xt (or gather buf in low tier)
  float* h1     = xtg + (useXT ? SZ_XT : SZ_G);
  float* h2     = h1 + Mc * 1024;
  float* pooled = h2 + Mc * 1024;
  float* ctx    = pooled + (size_t)PC * 256 * 1024;
  float* xs1    = ctx + SZ_CTX;
  float* xs2    = xs1 + SZ_XS;
  float* ssc    = xs2 + SZ_XS;
  float* ssh    = ssc + SZ_SS;
  float* partA  = ssh + SZ_SS;
  float* partB  = partA + (Mc / 128) * 1024 * 2;
  u32*   ctxp   = (u32*)(partB + (Mc / 128) * 1024 * 2);

  // pre-split all 15 weight matrices into gload layout
  k_wsplit<<<(3 * 1048576) / 256, 256, 0, stream>>>(cw, wpl, 3 * 1048576);
  k_wsplit<<<(12 * 1048576) / 256, 256, 0, stream>>>(lw, wpl + 3ull * 1048576,
                                                     12 * 1048576);
  if (useXT) k_transpose<<<dim3(256, 8), 256, 0, stream>>>(x, xtg);
  k_xsums<<<196, 256, 0, stream>>>(x, xs1, xs2);
  k_stats1<<<dim3(25, 4), 256, 0, stream>>>(xs1, xs2, bng, bnb, ssc, ssh);

  const dim3 gconv((int)(Mc / 128), 8);
  const dim3 gp3((int)(PC * 256 / 128), 8);

  for (int ch = 0; ch < NCH; ++ch) {
    const int pbase = ch * PC;
    // conv1: A from xt (BN1 affine from global ssc/ssh), stats -> partA
    if (useXT) {
      k_mg<2, true><<<gconv, 256, 0, stream>>>(xtg, wpl, cb, h1, ssc, ssh,
          nullptr, nullptr, nullptr, pbase, partA);
    } else {
      k_gather<<<(int)(Mc / 16), 256, 0, stream>>>(x, ssc, ssh, xtg, pbase);
      k_mg<0, true><<<gconv, 256, 0, stream>>>(xtg, wpl, cb, h1, nullptr, nullptr,
          nullptr, nullptr, nullptr, pbase, partA);
    }
    // conv2: BN2 finalized in-block from partA; stats -> partB
    k_mg<1, true><<<gconv, 256, 0, stream>>>(h1, wpl + 1ull * 1048576, cb + CC,
        h2, nullptr, nullptr, bng + CC, bnb + CC, partA, pbase, partB);
    // BN3 finalized in k_pool from partB; pool -> pooled
    k_pool<<<PC * 256, 256, 0, stream>>>(h2, partB, bng + 2 * CC, bnb + 2 * CC,
                                         pooled, pbase);
    // conv3 on pooled rows -> ctx slice
    k_mg<0, false><<<gp3, 256, 0, stream>>>(pooled, wpl + 2ull * 1048576,
        cb + 2 * CC, ctx + (size_t)pbase * 256 * CC, nullptr, nullptr,
        nullptr, nullptr, nullptr, 0, nullptr);
  }

  if (useCP) {
    k_wsplit<<<(6400 * 1024) / 256, 256, 0, stream>>>(ctx, ctxp, 6400 * 1024);
    k_heads<3><<<dim3(16, 120), 256, 0, stream>>>(ctx, ctxp, wpl + 3ull * 1048576, lb, out);
  } else {
    k_heads<0><<<dim3(16, 120), 256, 0, stream>>>(ctx, nullptr, wpl + 3ull * 1048576, lb, out);
  }
}

// Round 9
// 1606.632 us; speedup vs baseline: 1.1652x; 1.1652x over previous
//
#include <hip/hip_runtime.h>
#include <hip/hip_bf16.h>
#include <stdint.h>

#define BB 256
#define CC 1024
#define NP 25
#define EPS 1e-5f

typedef __attribute__((ext_vector_type(8))) short bf16x8;
typedef __attribute__((ext_vector_type(4))) float f32x4;
typedef unsigned int u32;

#define MFMA16(A, B, C) __builtin_amdgcn_mfma_f32_16x16x32_bf16(A, B, C, 0, 0, 0)

// async global->LDS, 16B per lane; LDS dest = wave-uniform base + lane*16
__device__ __forceinline__ void gload16(const u32* g, u32* l)
{
  __builtin_amdgcn_global_load_lds(
      (const __attribute__((address_space(1))) u32*)g,
      (__attribute__((address_space(3))) u32*)l, 16, 0, 0);
}

// ---------------------------------------------------------------- utils

__device__ __forceinline__ void head_entry(int j, int* pp, int* ww)
{
  int cnt = 0;
  for (int y1 = 0; y1 < 5; y1++)
    for (int x1 = 0; x1 < 5; x1++) {
      int p = y1 * 5 + x1;
      int y2 = y1 + 2, x2 = x1 + 2;
      if (y2 == 2 || y2 == 3)
        for (int s = 0; s < 3; s++) { if (y2 + s + 1 > 6) break; if (cnt == j) { *pp = p; *ww = 0 + s; return; } cnt++; }
      if (y1 == 3 || y1 == 4)
        for (int s = 0; s < 3; s++) { if (y1 - (s + 1) < 0) break; if (cnt == j) { *pp = p; *ww = 3 + s; return; } cnt++; }
      if (x2 == 2 || x2 == 3)
        for (int s = 0; s < 3; s++) { if (x2 + s + 1 > 6) break; if (cnt == j) { *pp = p; *ww = 6 + s; return; } cnt++; }
      if (x1 == 3 || x1 == 4)
        for (int s = 0; s < 3; s++) { if (x1 - (s + 1) < 0) break; if (cnt == j) { *pp = p; *ww = 9 + s; return; } cnt++; }
    }
}

// split fp32 -> hi bf16 (truncate) + lo bf16 (remainder); pack pairs into u32
__device__ __forceinline__ void split_f4(float4 f, uint2& h, uint2& l)
{
  u32 ux = __float_as_uint(f.x), uy = __float_as_uint(f.y);
  u32 uz = __float_as_uint(f.z), uw = __float_as_uint(f.w);
  h.x = (ux >> 16) | (uy & 0xFFFF0000u);
  h.y = (uz >> 16) | (uw & 0xFFFF0000u);
  float lx = f.x - __uint_as_float(ux & 0xFFFF0000u);
  float ly = f.y - __uint_as_float(uy & 0xFFFF0000u);
  float lz = f.z - __uint_as_float(uz & 0xFFFF0000u);
  float lw = f.w - __uint_as_float(uw & 0xFFFF0000u);
  l.x = (__float_as_uint(lx) >> 16) | (__float_as_uint(ly) & 0xFFFF0000u);
  l.y = (__float_as_uint(lz) >> 16) | (__float_as_uint(lw) & 0xFFFF0000u);
}

// ------------------------------------------------- layer-1 stats from x

__global__ void k_xsums(const float* __restrict__ x, float* __restrict__ xs1,
                        float* __restrict__ xs2)
{
  int pos = blockIdx.x * 256 + threadIdx.x;   // < 50176
  float s1 = 0.f, s2 = 0.f;
  for (int b = 0; b < BB; b++) {
    float v = x[(size_t)b * 50176 + pos];
    s1 += v; s2 = fmaf(v, v, s2);
  }
  xs1[pos] = s1; xs2[pos] = s2;
}

__global__ void k_stats1(const float* __restrict__ xs1, const float* __restrict__ xs2,
                         const float* __restrict__ gam, const float* __restrict__ bet,
                         float* __restrict__ ssc, float* __restrict__ ssh)
{
  int p = blockIdx.x;
  int c = blockIdx.y * 256 + threadIdx.x;
  int y1 = p / 5, x1 = p % 5;
  float s1 = 0.f, s2 = 0.f;
  for (int dy = 0; dy < 3; dy++)
    for (int dx = 0; dx < 3; dx++) {
      int pos = c * 49 + (y1 + dy) * 7 + (x1 + dx);
      s1 += xs1[pos]; s2 += xs2[pos];
    }
  const float inv = 1.0f / 2304.0f;
  float mean = s1 * inv;
  float var  = s2 * inv - mean * mean;
  float rs   = rsqrtf(var + EPS);
  float sc   = rs * gam[c];
  ssc[(size_t)p * CC + c] = sc;
  ssh[(size_t)p * CC + c] = bet[c] - mean * sc;
}

// ------------------------- one-time x transpose: x[b][c][yx] -> xt[b][yx][c]

__global__ void k_transpose(const float* __restrict__ x, float* __restrict__ xt)
{
  __shared__ float tile[128][51];
  int b = blockIdx.x, cg = blockIdx.y;
  const float* src = x + (size_t)b * 50176 + (size_t)cg * 128 * 49;
  for (int idx = threadIdx.x; idx < 6272; idx += 256)
    tile[idx / 49][idx % 49] = src[idx];
  __syncthreads();
  float* dst = xt + (size_t)b * 49 * 1024 + cg * 128;
  for (int pp = 0; pp < 50; pp += 2) {
    int p = pp + (threadIdx.x >> 7);
    int i = threadIdx.x & 127;
    if (p < 49) dst[(size_t)p * 1024 + i] = tile[i][p];
  }
}

// -------------- fallback patch gather + BN1 affine + relu (small-ws tier)

__global__ void k_gather(const float* __restrict__ x, const float* __restrict__ ssc,
                         const float* __restrict__ ssh, float* __restrict__ out,
                         int pbase)
{
  int tid = threadIdx.x;
  int r0 = blockIdx.x * 16;
  for (int rr = 0; rr < 16; rr++) {
    int row = r0 + rr;
    int pl = row / 2304;
    int b  = (row / 9) & 255;
    int yx = row % 9;
    int pg = pbase + pl;
    int pos = (pg / 5 + yx / 3) * 7 + (pg % 5) + (yx % 3);
    const float* xb  = x + (size_t)b * CC * 49 + pos;
    const float* scp = ssc + (size_t)pg * CC;
    const float* shp = ssh + (size_t)pg * CC;
    float* op = out + (size_t)row * CC;
    #pragma unroll
    for (int q = 0; q < 4; q++) {
      int c = q * 256 + tid;
      float v = xb[(size_t)c * 49];
      op[c] = fmaxf(fmaf(v, scp[c], shp[c]), 0.f);
    }
  }
}

// ---------- weight/ctx pre-split into gload-ready interleaved hi/lo layout
// out row = 1024 u32: [slab 0..31][ 16 u32 hi pairs | 16 u32 lo pairs ]

__global__ void k_wsplit(const float* __restrict__ w, u32* __restrict__ dst, int total)
{
  int g = blockIdx.x * 256 + threadIdx.x;
  if (g >= total) return;
  int row = g >> 10;
  int rem = g & 1023;
  int slab = rem >> 5, j = rem & 31;
  int lo = j >> 4, jj = j & 15;
  const float* src = w + ((size_t)row << 10) + slab * 32 + 2 * jj;
  float f0 = src[0], f1 = src[1];
  u32 u0 = __float_as_uint(f0), u1 = __float_as_uint(f1);
  u32 v;
  if (lo == 0) {
    v = (u0 >> 16) | (u1 & 0xFFFF0000u);
  } else {
    float l0 = f0 - __uint_as_float(u0 & 0xFFFF0000u);
    float l1 = f1 - __uint_as_float(u1 & 0xFFFF0000u);
    v = (__float_as_uint(l0) >> 16) | (__float_as_uint(l1) & 0xFFFF0000u);
  }
  dst[g] = v;
}

// -------- BN3 stats-final (from partB) + affine + relu + 3x3 mean pooling

__global__ void k_pool(const float* __restrict__ h, const float* __restrict__ part,
                       const float* __restrict__ gam, const float* __restrict__ bet,
                       float* __restrict__ apool, int pbase)
{
  int row = blockIdx.x;                 // pl*256 + b (local to chunk)
  int pl = row >> 8;
  int c = threadIdx.x * 4;
  float s1[4] = {0.f, 0.f, 0.f, 0.f}, s2[4] = {0.f, 0.f, 0.f, 0.f};
  for (int mb = 0; mb < 18; mb++) {
    const float* pp = part + ((size_t)(pl * 18 + mb) * CC + c) * 2;
    #pragma unroll
    for (int e = 0; e < 4; e++) { s1[e] += pp[2 * e]; s2[e] += pp[2 * e + 1]; }
  }
  float4 sc, sh;
  {
    const float inv = 1.0f / 2304.0f;
    float scv[4], shv[4];
    #pragma unroll
    for (int e = 0; e < 4; e++) {
      float mean = s1[e] * inv;
      float var  = s2[e] * inv - mean * mean;
      float rs   = rsqrtf(var + EPS);
      float g    = rs * gam[c + e];
      scv[e] = g; shv[e] = bet[c + e] - mean * g;
    }
    sc = make_float4(scv[0], scv[1], scv[2], scv[3]);
    sh = make_float4(shv[0], shv[1], shv[2], shv[3]);
  }
  const float* hp = h + (size_t)row * 9 * CC + c;
  float4 s = {0.f, 0.f, 0.f, 0.f};
  #pragma unroll
  for (int yx = 0; yx < 9; yx++) {
    float4 v = *(const float4*)(hp + (size_t)yx * CC);
    s.x += fmaxf(fmaf(v.x, sc.x, sh.x), 0.f);
    s.y += fmaxf(fmaf(v.y, sc.y, sh.y), 0.f);
    s.z += fmaxf(fmaf(v.z, sc.z, sh.z), 0.f);
    s.w += fmaxf(fmaf(v.w, sc.w, sh.w), 0.f);
  }
  const float inv9 = 1.0f / 9.0f;
  float4 o = { s.x * inv9, s.y * inv9, s.z * inv9, s.w * inv9 };
  *(float4*)(apool + (size_t)row * CC + c) = o;
}

// ------------------------------------------------------------ MFMA GEMM core
// C[m][n] = sum_k f(A[m][k]) * B[n][k] + bias[n]
// split-bf16: acc += ah*bh + al*bh + ah*bl  (fp32 MFMA accumulate)
// LDS layout per 128-row tile: row*32 u32, granule g (16B) at phys g^(row&7).
// MODE: 0 = A fp32 reg-staged, identity rows
//       1 = A fp32 reg-staged + BN affine/relu with stats finalized IN-BLOCK
//           from partIn (18 float2 rows per patch) into LDS
//       2 = A fp32 reg-staged + BN1 affine/relu (global ssc/ssh), xt row-map
//       3 = A pre-split, gload (heads)
// B always pre-split planes via global_load_lds.
// STATS: emit per-block column sum/sumsq to partOut[mb][col][2].

template<int MODE, bool STATS>
__device__ __forceinline__ void mg_body(
    const float* __restrict__ Af, const u32* __restrict__ Agl,
    const u32* __restrict__ Bp, const float* __restrict__ bias,
    float* __restrict__ Cmat, const float* __restrict__ ssc,
    const float* __restrict__ ssh, const float* __restrict__ gam,
    const float* __restrict__ bet, const float* __restrict__ partIn,
    int pbase, int m0, int n0,
    float* __restrict__ partOut, int mb)
{
  __shared__ u32 sA[2][4096];
  __shared__ u32 sB[2][4096];
  __shared__ float sr1[4][64];
  __shared__ float sr2[4][64];

  const int t = threadIdx.x;
  const int l = t & 63, wv = t >> 6;
  const int lr = l & 15, lk = l >> 4;
  const int wm = (wv >> 1) * 64, wn = (wv & 1) * 64;

  // fragment read offsets (u32) with granule XOR swizzle
  int fAh[4], fAl[4], fBh[4], fBl[4];
  #pragma unroll
  for (int i = 0; i < 4; i++) {
    int Ra = wm + i * 16 + lr;
    int Rb = wn + i * 16 + lr;
    fAh[i] = Ra * 32 + ((lk ^ (Ra & 7)) << 2);
    fAl[i] = Ra * 32 + (((4 + lk) ^ (Ra & 7)) << 2);
    fBh[i] = Rb * 32 + ((lk ^ (Rb & 7)) << 2);
    fBl[i] = Rb * 32 + (((4 + lk) ^ (Rb & 7)) << 2);
  }

  // gload addressing: wave covers rows wv*32..wv*32+31 in 4 chunks of 8 rows
  int growq[4], ggq[4];
  #pragma unroll
  for (int q = 0; q < 4; q++) {
    int rr = wv * 32 + q * 8 + (l >> 3);
    growq[q] = rr;
    ggq[q] = (((l & 7) ^ (rr & 7)) << 2);
  }
  const u32* Brow = Bp + (size_t)n0 * 1024;
  const u32* Agr  = (MODE == 3) ? (Agl + (size_t)m0 * 1024) : nullptr;

  // reg-staging setup (MODE<3): thread = (row sr, 16-float half sh_)
  const int sr = t >> 1, sh_ = t & 1;
  const float *arow = nullptr, *scp = nullptr, *shp = nullptr;
  int wA[4] = {0, 0, 0, 0};

  // MODE 1: finalize BN stats in-block into LDS (same order as k_statsfin)
  __shared__ float sSC[(MODE == 1) ? 1024 : 1];
  __shared__ float sSH[(MODE == 1) ? 1024 : 1];
  if (MODE == 1) {
    int pl = m0 / 2304;
    for (int c = t; c < 1024; c += 256) {
      float s1 = 0.f, s2 = 0.f;
      for (int mb2 = 0; mb2 < 18; mb2++) {
        const float* pp = partIn + ((size_t)(pl * 18 + mb2) * CC + c) * 2;
        s1 += pp[0]; s2 += pp[1];
      }
      const float inv = 1.0f / 2304.0f;
      float mean = s1 * inv;
      float var  = s2 * inv - mean * mean;
      float rs   = rsqrtf(var + EPS);
      float g    = rs * gam[c];
      sSC[c] = g;
      sSH[c] = bet[c] - mean * g;
    }
    __syncthreads();
  }

  if (MODE < 3) {
    wA[0] = sr * 32 + (((2 * sh_)     ^ (sr & 7)) << 2);
    wA[1] = sr * 32 + (((2 * sh_ + 1) ^ (sr & 7)) << 2);
    wA[2] = sr * 32 + (((4 + 2 * sh_) ^ (sr & 7)) << 2);
    wA[3] = sr * 32 + (((5 + 2 * sh_) ^ (sr & 7)) << 2);
    if (MODE == 2) {
      int pl = m0 / 2304, pg = pbase + pl;
      int q = m0 + sr - pl * 2304;
      int b = q / 9, yx = q % 9;
      int pos = (pg / 5 + yx / 3) * 7 + (pg % 5) + (yx % 3);
      arow = Af + ((size_t)b * 49 + pos) * CC + sh_ * 16;
      scp = ssc + (size_t)pg * CC + sh_ * 16;
      shp = ssh + (size_t)pg * CC + sh_ * 16;
    } else {
      arow = Af + (size_t)(m0 + sr) * CC + sh_ * 16;
      if (MODE == 1) {
        scp = &sSC[sh_ * 16];
        shp = &sSH[sh_ * 16];
      }
    }
  }

  f32x4 acc[4][4];
  #pragma unroll
  for (int i = 0; i < 4; i++)
    #pragma unroll
    for (int j = 0; j < 4; j++) { f32x4 z = {0.f, 0.f, 0.f, 0.f}; acc[i][j] = z; }

  float4 areg[4];

  // prologue: stage slab 0
  {
    #pragma unroll
    for (int q = 0; q < 4; q++)
      gload16(Brow + (size_t)growq[q] * 1024 + ggq[q],
              &sB[0][(wv * 32 + q * 8) * 32]);
    if (MODE == 3) {
      #pragma unroll
      for (int q = 0; q < 4; q++)
        gload16(Agr + (size_t)growq[q] * 1024 + ggq[q],
                &sA[0][(wv * 32 + q * 8) * 32]);
    } else {
      areg[0] = *(const float4*)(arow + 0);
      areg[1] = *(const float4*)(arow + 4);
      areg[2] = *(const float4*)(arow + 8);
      areg[3] = *(const float4*)(arow + 12);
      if (MODE == 1 || MODE == 2) {
        #pragma unroll
        for (int v = 0; v < 4; v++) {
          float4 s = *(const float4*)(scp + v * 4);
          float4 h = *(const float4*)(shp + v * 4);
          areg[v].x = fmaxf(fmaf(areg[v].x, s.x, h.x), 0.f);
          areg[v].y = fmaxf(fmaf(areg[v].y, s.y, h.y), 0.f);
          areg[v].z = fmaxf(fmaf(areg[v].z, s.z, h.z), 0.f);
          areg[v].w = fmaxf(fmaf(areg[v].w, s.w, h.w), 0.f);
        }
      }
      uint2 h0, l0, h1, l1, h2, l2, h3, l3;
      split_f4(areg[0], h0, l0); split_f4(areg[1], h1, l1);
      split_f4(areg[2], h2, l2); split_f4(areg[3], h3, l3);
      *(uint4*)&sA[0][wA[0]] = make_uint4(h0.x, h0.y, h1.x, h1.y);
      *(uint4*)&sA[0][wA[1]] = make_uint4(h2.x, h2.y, h3.x, h3.y);
      *(uint4*)&sA[0][wA[2]] = make_uint4(l0.x, l0.y, l1.x, l1.y);
      *(uint4*)&sA[0][wA[3]] = make_uint4(l2.x, l2.y, l3.x, l3.y);
    }
  }
  __syncthreads();

  #pragma unroll 1
  for (int it = 0; it < 32; ++it) {
    const int cur = it & 1, nxt = cur ^ 1;
    const int kk2 = (it + 1) << 5;
    const bool pf = (it < 31);
    if (pf) {
      int so = kk2;
      #pragma unroll
      for (int q = 0; q < 4; q++)
        gload16(Brow + (size_t)growq[q] * 1024 + so + ggq[q],
                &sB[nxt][(wv * 32 + q * 8) * 32]);
      if (MODE == 3) {
        #pragma unroll
        for (int q = 0; q < 4; q++)
          gload16(Agr + (size_t)growq[q] * 1024 + so + ggq[q],
                  &sA[nxt][(wv * 32 + q * 8) * 32]);
      } else {
        areg[0] = *(const float4*)(arow + kk2);
        areg[1] = *(const float4*)(arow + kk2 + 4);
        areg[2] = *(const float4*)(arow + kk2 + 8);
        areg[3] = *(const float4*)(arow + kk2 + 12);
      }
    }
    // compute on cur
    bf16x8 Ah[4], Al_[4], Bh[4], Bl[4];
    #pragma unroll
    for (int i = 0; i < 4; i++) {
      Ah[i]  = *(const bf16x8*)&sA[cur][fAh[i]];
      Al_[i] = *(const bf16x8*)&sA[cur][fAl[i]];
      Bh[i]  = *(const bf16x8*)&sB[cur][fBh[i]];
      Bl[i]  = *(const bf16x8*)&sB[cur][fBl[i]];
    }
    #pragma unroll
    for (int i = 0; i < 4; i++)
      #pragma unroll
      for (int j = 0; j < 4; j++) {
        acc[i][j] = MFMA16(Ah[i],  Bh[j], acc[i][j]);
        acc[i][j] = MFMA16(Al_[i], Bh[j], acc[i][j]);
        acc[i][j] = MFMA16(Ah[i],  Bl[j], acc[i][j]);
      }
    if (pf && MODE < 3) {
      if (MODE == 1 || MODE == 2) {
        #pragma unroll
        for (int v = 0; v < 4; v++) {
          float4 s = *(const float4*)(scp + kk2 + v * 4);
          float4 h = *(const float4*)(shp + kk2 + v * 4);
          areg[v].x = fmaxf(fmaf(areg[v].x, s.x, h.x), 0.f);
          areg[v].y = fmaxf(fmaf(areg[v].y, s.y, h.y), 0.f);
          areg[v].z = fmaxf(fmaf(areg[v].z, s.z, h.z), 0.f);
          areg[v].w = fmaxf(fmaf(areg[v].w, s.w, h.w), 0.f);
        }
      }
      uint2 h0, l0, h1, l1, h2, l2, h3, l3;
      split_f4(areg[0], h0, l0); split_f4(areg[1], h1, l1);
      split_f4(areg[2], h2, l2); split_f4(areg[3], h3, l3);
      *(uint4*)&sA[nxt][wA[0]] = make_uint4(h0.x, h0.y, h1.x, h1.y);
      *(uint4*)&sA[nxt][wA[1]] = make_uint4(h2.x, h2.y, h3.x, h3.y);
      *(uint4*)&sA[nxt][wA[2]] = make_uint4(l0.x, l0.y, l1.x, l1.y);
      *(uint4*)&sA[nxt][wA[3]] = make_uint4(l2.x, l2.y, l3.x, l3.y);
    }
    __syncthreads();
  }

  // epilogue: D row = lk*4 + reg, col = lr [m89 layout]; optional col stats
  float st1[4], st2[4];
  #pragma unroll
  for (int j = 0; j < 4; j++) { st1[j] = 0.f; st2[j] = 0.f; }
  #pragma unroll
  for (int j = 0; j < 4; j++) {
    int ocol = n0 + wn + j * 16 + lr;
    float bj = bias[ocol];
    #pragma unroll
    for (int i = 0; i < 4; i++) {
      int orow = m0 + wm + i * 16 + lk * 4;
      float* cp = Cmat + (size_t)orow * CC + ocol;
      #pragma unroll
      for (int reg = 0; reg < 4; reg++) {
        float v = acc[i][j][reg] + bj;
        cp[(size_t)reg * CC] = v;
        if (STATS) { st1[j] += v; st2[j] = fmaf(v, v, st2[j]); }
      }
    }
  }
  if (STATS) {
    #pragma unroll
    for (int j = 0; j < 4; j++) {
      st1[j] += __shfl_xor(st1[j], 16, 64);
      st1[j] += __shfl_xor(st1[j], 32, 64);
      st2[j] += __shfl_xor(st2[j], 16, 64);
      st2[j] += __shfl_xor(st2[j], 32, 64);
    }
    if (lk == 0) {
      #pragma unroll
      for (int j = 0; j < 4; j++) {
        sr1[wv][j * 16 + lr] = st1[j];
        sr2[wv][j * 16 + lr] = st2[j];
      }
    }
    __syncthreads();
    if (t < 128) {
      int ch = t >> 6, c6 = t & 63;
      float a1 = sr1[ch][c6] + sr1[ch + 2][c6];
      float a2 = sr2[ch][c6] + sr2[ch + 2][c6];
      float2 o = { a1, a2 };
      *(float2*)(partOut + ((size_t)mb * CC + n0 + t) * 2) = o;
    }
  }
}

template<int MODE, bool STATS>
__global__ __launch_bounds__(256, 2)
void k_mg(const float* __restrict__ Af, const u32* __restrict__ Bp,
          const float* __restrict__ bias, float* __restrict__ Cmat,
          const float* __restrict__ ssc, const float* __restrict__ ssh,
          const float* __restrict__ gam, const float* __restrict__ bet,
          const float* __restrict__ partIn, int pbase,
          float* __restrict__ partOut)
{
  mg_body<MODE, STATS>(Af, nullptr, Bp, bias, Cmat, ssc, ssh, gam, bet,
                       partIn, pbase, blockIdx.x * 128, blockIdx.y * 128,
                       partOut, blockIdx.x);
}

template<int MODE>
__global__ __launch_bounds__(256, 2)
void k_heads(const float* __restrict__ ctx, const u32* __restrict__ ctxp,
             const u32* __restrict__ wplh, const float* __restrict__ lb,
             float* __restrict__ out)
{
  int p, w;
  head_entry(blockIdx.y, &p, &w);
  mg_body<MODE, false>(ctx + (size_t)p * BB * CC,
                       ctxp ? ctxp + (size_t)p * BB * 1024 : nullptr,
                       wplh + (size_t)w * 1048576,
                       lb + (size_t)w * CC,
                       out + (size_t)blockIdx.y * BB * CC,
                       nullptr, nullptr, nullptr, nullptr, nullptr, 0,
                       (blockIdx.x >> 3) * 128, (blockIdx.x & 7) * 128,
                       nullptr, 0);
}

// ---------------------------------------------------------------- launch

extern "C" void kernel_launch(void* const* d_in, const int* in_sizes, int n_in,
                              void* d_out, int out_size, void* d_ws, size_t ws_size,
                              hipStream_t stream)
{
  const float* x   = (const float*)d_in[0];
  const float* bng = (const float*)d_in[1];
  const float* bnb = (const float*)d_in[2];
  const float* cw  = (const float*)d_in[3];
  const float* cb  = (const float*)d_in[4];
  const float* lw  = (const float*)d_in[5];
  const float* lb  = (const float*)d_in[6];
  float* out = (float*)d_out;
  float* ws  = (float*)d_ws;

  const size_t W = ws_size / 4;           // 4-byte words
  const size_t SZ_WPL  = 15ull * 1048576;
  const size_t SZ_XT   = 256ull * 49 * 1024;
  const size_t SZ_G    = 2304ull * 1024;        // gather buf (PC=1 fallback)
  const size_t SZ_CTX  = 6400ull * 1024;
  const size_t SZ_POOL = 6400ull * 1024;        // pooled, always full-25
  const size_t SZ_XS   = 50176;
  const size_t SZ_SS   = 25ull * 1024;
  const size_t SZ_PA   = 25ull * 18 * 1024 * 2; // partA, always full-25

  auto need = [&](int pc1, int pc2, bool xt, bool cp) -> size_t {
    size_t h1w = (size_t)pc1 * 2304 * 1024;
    size_t h2w = (size_t)pc2 * 2304 * 1024;
    return SZ_WPL + (xt ? SZ_XT : SZ_G) + h1w + h2w + SZ_POOL + SZ_CTX
         + 2 * SZ_XS + 2 * SZ_SS + SZ_PA
         + (size_t)pc2 * 18 * 1024 * 2 + (cp ? SZ_CTX : 0);
  };
  int PC1, PC2; bool useXT, useCP;
  if      (W >= need(25, 25, true, true)) { PC1 = 25; PC2 = 25; useXT = true;  useCP = true;  }
  else if (W >= need(25,  5, true, true)) { PC1 = 25; PC2 = 5;  useXT = true;  useCP = true;  }
  else if (W >= need( 5,  5, true, true)) { PC1 = 5;  PC2 = 5;  useXT = true;  useCP = true;  }
  else if (W >= need( 5,  5, true, false)){ PC1 = 5;  PC2 = 5;  useXT = true;  useCP = false; }
  else if (W >= need( 1,  1, true, false)){ PC1 = 1;  PC2 = 1;  useXT = true;  useCP = false; }
  else                                    { PC1 = 1;  PC2 = 1;  useXT = false; useCP = false; }
  const bool bigH1 = (PC1 == 25);

  u32*   wpl    = (u32*)ws;
  float* xtg    = (float*)(wpl + SZ_WPL);       // xt (or gather buf in low tier)
  float* h1     = xtg + (useXT ? SZ_XT : SZ_G);
  float* h2     = h1 + (size_t)PC1 * 2304 * 1024;
  float* pooled = h2 + (size_t)PC2 * 2304 * 1024;
  float* ctx    = pooled + SZ_POOL;
  float* xs1    = ctx + SZ_CTX;
  float* xs2    = xs1 + SZ_XS;
  float* ssc    = xs2 + SZ_XS;
  float* ssh    = ssc + SZ_SS;
  float* partA  = ssh + SZ_SS;
  float* partB  = partA + SZ_PA;
  u32*   ctxp   = (u32*)(partB + (size_t)PC2 * 18 * 1024 * 2);

  // pre-split all 15 weight matrices into gload layout
  k_wsplit<<<(3 * 1048576) / 256, 256, 0, stream>>>(cw, wpl, 3 * 1048576);
  k_wsplit<<<(12 * 1048576) / 256, 256, 0, stream>>>(lw, wpl + 3ull * 1048576,
                                                     12 * 1048576);
  if (useXT) k_transpose<<<dim3(256, 8), 256, 0, stream>>>(x, xtg);
  k_xsums<<<196, 256, 0, stream>>>(x, xs1, xs2);
  k_stats1<<<dim3(25, 4), 256, 0, stream>>>(xs1, xs2, bng, bnb, ssc, ssh);

  // conv1 for ALL patches in one launch when h1 is full-size
  if (bigH1) {
    k_mg<2, true><<<dim3(25 * 18, 8), 256, 0, stream>>>(
        xtg, wpl, cb, h1, ssc, ssh, nullptr, nullptr, nullptr, 0, partA);
  }

  for (int pbase = 0; pbase < NP; pbase += PC2) {
    const int mc = PC2 * 2304;
    const dim3 gconv(mc / 128, 8);
    float* partAc = partA + (size_t)pbase * 18 * 1024 * 2;
    // conv1 (chunked tiers only)
    if (!bigH1) {
      if (useXT) {
        k_mg<2, true><<<gconv, 256, 0, stream>>>(xtg, wpl, cb, h1, ssc, ssh,
            nullptr, nullptr, nullptr, pbase, partAc);
      } else {
        k_gather<<<mc / 16, 256, 0, stream>>>(x, ssc, ssh, xtg, pbase);
        k_mg<0, true><<<gconv, 256, 0, stream>>>(xtg, wpl, cb, h1, nullptr,
            nullptr, nullptr, nullptr, nullptr, pbase, partAc);
      }
    }
    const float* Ain = bigH1 ? h1 + (size_t)pbase * 2304 * 1024 : h1;
    // conv2: BN2 finalized in-block from partA slice; stats -> partB
    k_mg<1, true><<<gconv, 256, 0, stream>>>(Ain, wpl + 1ull * 1048576, cb + CC,
        h2, nullptr, nullptr, bng + CC, bnb + CC, partAc, pbase, partB);
    // BN3 finalized in k_pool from partB; pool -> pooled slice
    k_pool<<<PC2 * 256, 256, 0, stream>>>(h2, partB, bng + 2 * CC, bnb + 2 * CC,
                                          pooled + (size_t)pbase * 256 * 1024,
                                          pbase);
  }

  // conv3 for ALL pooled rows in one launch (400 blocks)
  k_mg<0, false><<<dim3(50, 8), 256, 0, stream>>>(pooled, wpl + 2ull * 1048576,
      cb + 2 * CC, ctx, nullptr, nullptr, nullptr, nullptr, nullptr, 0, nullptr);

  if (useCP) {
    k_wsplit<<<(6400 * 1024) / 256, 256, 0, stream>>>(ctx, ctxp, 6400 * 1024);
    k_heads<3><<<dim3(16, 120), 256, 0, stream>>>(ctx, ctxp, wpl + 3ull * 1048576, lb, out);
  } else {
    k_heads<0><<<dim3(16, 120), 256, 0, stream>>>(ctx, nullptr, wpl + 3ull * 1048576, lb, out);
  }
}

// Round 10
// 1493.276 us; speedup vs baseline: 1.2536x; 1.0759x over previous
//
#include <hip/hip_runtime.h>
#include <hip/hip_bf16.h>
#include <stdint.h>

#define BB 256
#define CC 1024
#define NP 25
#define EPS 1e-5f

typedef __attribute__((ext_vector_type(8))) short bf16x8;
typedef __attribute__((ext_vector_type(4))) float f32x4;
typedef unsigned int u32;

#define MFMA16(A, B, C) __builtin_amdgcn_mfma_f32_16x16x32_bf16(A, B, C, 0, 0, 0)

// async global->LDS, 16B per lane; LDS dest = wave-uniform base + lane*16
__device__ __forceinline__ void gload16(const u32* g, u32* l)
{
  __builtin_amdgcn_global_load_lds(
      (const __attribute__((address_space(1))) u32*)g,
      (__attribute__((address_space(3))) u32*)l, 16, 0, 0);
}

// ---------------------------------------------------------------- utils

__device__ __forceinline__ void head_entry(int j, int* pp, int* ww)
{
  int cnt = 0;
  for (int y1 = 0; y1 < 5; y1++)
    for (int x1 = 0; x1 < 5; x1++) {
      int p = y1 * 5 + x1;
      int y2 = y1 + 2, x2 = x1 + 2;
      if (y2 == 2 || y2 == 3)
        for (int s = 0; s < 3; s++) { if (y2 + s + 1 > 6) break; if (cnt == j) { *pp = p; *ww = 0 + s; return; } cnt++; }
      if (y1 == 3 || y1 == 4)
        for (int s = 0; s < 3; s++) { if (y1 - (s + 1) < 0) break; if (cnt == j) { *pp = p; *ww = 3 + s; return; } cnt++; }
      if (x2 == 2 || x2 == 3)
        for (int s = 0; s < 3; s++) { if (x2 + s + 1 > 6) break; if (cnt == j) { *pp = p; *ww = 6 + s; return; } cnt++; }
      if (x1 == 3 || x1 == 4)
        for (int s = 0; s < 3; s++) { if (x1 - (s + 1) < 0) break; if (cnt == j) { *pp = p; *ww = 9 + s; return; } cnt++; }
    }
}

// split fp32 -> hi bf16 (truncate) + lo bf16 (remainder); pack pairs into u32
__device__ __forceinline__ void split_f4(float4 f, uint2& h, uint2& l)
{
  u32 ux = __float_as_uint(f.x), uy = __float_as_uint(f.y);
  u32 uz = __float_as_uint(f.z), uw = __float_as_uint(f.w);
  h.x = (ux >> 16) | (uy & 0xFFFF0000u);
  h.y = (uz >> 16) | (uw & 0xFFFF0000u);
  float lx = f.x - __uint_as_float(ux & 0xFFFF0000u);
  float ly = f.y - __uint_as_float(uy & 0xFFFF0000u);
  float lz = f.z - __uint_as_float(uz & 0xFFFF0000u);
  float lw = f.w - __uint_as_float(uw & 0xFFFF0000u);
  l.x = (__float_as_uint(lx) >> 16) | (__float_as_uint(ly) & 0xFFFF0000u);
  l.y = (__float_as_uint(lz) >> 16) | (__float_as_uint(lw) & 0xFFFF0000u);
}

// ------------------------------------------------- layer-1 stats from x

__global__ void k_xsums(const float* __restrict__ x, float* __restrict__ xs1,
                        float* __restrict__ xs2)
{
  int pos = blockIdx.x * 256 + threadIdx.x;   // < 50176
  float s1 = 0.f, s2 = 0.f;
  for (int b = 0; b < BB; b++) {
    float v = x[(size_t)b * 50176 + pos];
    s1 += v; s2 = fmaf(v, v, s2);
  }
  xs1[pos] = s1; xs2[pos] = s2;
}

__global__ void k_stats1(const float* __restrict__ xs1, const float* __restrict__ xs2,
                         const float* __restrict__ gam, const float* __restrict__ bet,
                         float* __restrict__ ssc, float* __restrict__ ssh)
{
  int p = blockIdx.x;
  int c = blockIdx.y * 256 + threadIdx.x;
  int y1 = p / 5, x1 = p % 5;
  float s1 = 0.f, s2 = 0.f;
  for (int dy = 0; dy < 3; dy++)
    for (int dx = 0; dx < 3; dx++) {
      int pos = c * 49 + (y1 + dy) * 7 + (x1 + dx);
      s1 += xs1[pos]; s2 += xs2[pos];
    }
  const float inv = 1.0f / 2304.0f;
  float mean = s1 * inv;
  float var  = s2 * inv - mean * mean;
  float rs   = rsqrtf(var + EPS);
  float sc   = rs * gam[c];
  ssc[(size_t)p * CC + c] = sc;
  ssh[(size_t)p * CC + c] = bet[c] - mean * sc;
}

// ------------------------- one-time x transpose: x[b][c][yx] -> xt[b][yx][c]

__global__ void k_transpose(const float* __restrict__ x, float* __restrict__ xt)
{
  __shared__ float tile[128][51];
  int b = blockIdx.x, cg = blockIdx.y;
  const float* src = x + (size_t)b * 50176 + (size_t)cg * 128 * 49;
  for (int idx = threadIdx.x; idx < 6272; idx += 256)
    tile[idx / 49][idx % 49] = src[idx];
  __syncthreads();
  float* dst = xt + (size_t)b * 49 * 1024 + cg * 128;
  for (int pp = 0; pp < 50; pp += 2) {
    int p = pp + (threadIdx.x >> 7);
    int i = threadIdx.x & 127;
    if (p < 49) dst[(size_t)p * 1024 + i] = tile[i][p];
  }
}

// ---------- weight/ctx pre-split into gload-ready interleaved hi/lo layout
// out row = 1024 u32: [slab 0..31][ 16 u32 hi pairs | 16 u32 lo pairs ]

__global__ void k_wsplit(const float* __restrict__ w, u32* __restrict__ dst, int total)
{
  int g = blockIdx.x * 256 + threadIdx.x;
  if (g >= total) return;
  int row = g >> 10;
  int rem = g & 1023;
  int slab = rem >> 5, j = rem & 31;
  int lo = j >> 4, jj = j & 15;
  const float* src = w + ((size_t)row << 10) + slab * 32 + 2 * jj;
  float f0 = src[0], f1 = src[1];
  u32 u0 = __float_as_uint(f0), u1 = __float_as_uint(f1);
  u32 v;
  if (lo == 0) {
    v = (u0 >> 16) | (u1 & 0xFFFF0000u);
  } else {
    float l0 = f0 - __uint_as_float(u0 & 0xFFFF0000u);
    float l1 = f1 - __uint_as_float(u1 & 0xFFFF0000u);
    v = (__float_as_uint(l0) >> 16) | (__float_as_uint(l1) & 0xFFFF0000u);
  }
  dst[g] = v;
}

// ------------- A-operand affine+relu+split into gload layout
// MODE 0: src = fp32 rows (conv2 A); MODE 1: src = xt, patch row-map (conv1 A);
// MODE 2: src = x, strided reads (no-xt fallback).
// Affine per global patch pg from ssc/ssh.

template<int MODE>
__global__ void k_absplit(const float* __restrict__ src,
                          const float* __restrict__ ssc, const float* __restrict__ ssh,
                          u32* __restrict__ dst, int pbase)
{
  int r = blockIdx.x * 8 + (threadIdx.x >> 5);   // local row
  int slab = threadIdx.x & 31;
  int pg;
  const float* sp = nullptr;
  const float* xb = nullptr;
  if (MODE == 0) {
    pg = pbase + r / 2304;
    sp = src + (size_t)r * 1024 + slab * 32;
  } else {
    int pl = r / 2304, q = r - pl * 2304;
    pg = pbase + pl;
    int b = q / 9, yx = q - b * 9;
    int pos = (pg / 5 + yx / 3) * 7 + (pg % 5) + (yx % 3);
    if (MODE == 1) sp = src + ((size_t)b * 49 + pos) * 1024 + slab * 32;
    else           xb = src + (size_t)b * 50176 + (size_t)slab * 32 * 49 + pos;
  }
  const float* scp = ssc + (size_t)pg * CC + slab * 32;
  const float* shp = ssh + (size_t)pg * CC + slab * 32;
  u32 hi[16], lo[16];
  #pragma unroll
  for (int j = 0; j < 8; j++) {
    float4 f;
    if (MODE == 2) {
      f.x = xb[(size_t)(4 * j + 0) * 49]; f.y = xb[(size_t)(4 * j + 1) * 49];
      f.z = xb[(size_t)(4 * j + 2) * 49]; f.w = xb[(size_t)(4 * j + 3) * 49];
    } else {
      f = *(const float4*)(sp + 4 * j);
    }
    float4 s = *(const float4*)(scp + 4 * j);
    float4 h = *(const float4*)(shp + 4 * j);
    f.x = fmaxf(fmaf(f.x, s.x, h.x), 0.f);
    f.y = fmaxf(fmaf(f.y, s.y, h.y), 0.f);
    f.z = fmaxf(fmaf(f.z, s.z, h.z), 0.f);
    f.w = fmaxf(fmaf(f.w, s.w, h.w), 0.f);
    uint2 hh, ll;
    split_f4(f, hh, ll);
    hi[2 * j] = hh.x; hi[2 * j + 1] = hh.y;
    lo[2 * j] = ll.x; lo[2 * j + 1] = ll.y;
  }
  u32* op = dst + (size_t)r * 1024 + slab * 32;
  *(uint4*)(op + 0)  = make_uint4(hi[0], hi[1], hi[2], hi[3]);
  *(uint4*)(op + 4)  = make_uint4(hi[4], hi[5], hi[6], hi[7]);
  *(uint4*)(op + 8)  = make_uint4(hi[8], hi[9], hi[10], hi[11]);
  *(uint4*)(op + 12) = make_uint4(hi[12], hi[13], hi[14], hi[15]);
  *(uint4*)(op + 16) = make_uint4(lo[0], lo[1], lo[2], lo[3]);
  *(uint4*)(op + 20) = make_uint4(lo[4], lo[5], lo[6], lo[7]);
  *(uint4*)(op + 24) = make_uint4(lo[8], lo[9], lo[10], lo[11]);
  *(uint4*)(op + 28) = make_uint4(lo[12], lo[13], lo[14], lo[15]);
}

// ------------------- finalize BN stats from per-mblock partials (18/patch)

__global__ void k_statsfin(const float* __restrict__ part, const float* __restrict__ gam,
                           const float* __restrict__ bet, float* __restrict__ ssc,
                           float* __restrict__ ssh, int pbase)
{
  int pl = blockIdx.x;
  int c  = blockIdx.y * 256 + threadIdx.x;
  float s1 = 0.f, s2 = 0.f;
  for (int mb = 0; mb < 18; mb++) {
    const float* pp = part + ((size_t)(pl * 18 + mb) * CC + c) * 2;
    s1 += pp[0]; s2 += pp[1];
  }
  const float inv = 1.0f / 2304.0f;
  float mean = s1 * inv;
  float var  = s2 * inv - mean * mean;
  float rs   = rsqrtf(var + EPS);
  float sc   = rs * gam[c];
  int pg = pbase + pl;
  ssc[(size_t)pg * CC + c] = sc;
  ssh[(size_t)pg * CC + c] = bet[c] - mean * sc;
}

// ---- BN3 affine+relu + 3x3 mean pooling, output in split gload layout

__global__ void k_pool(const float* __restrict__ h, const float* __restrict__ ssc,
                       const float* __restrict__ ssh, u32* __restrict__ apool, int pbase)
{
  int row = blockIdx.x;                 // local: pl*256 + b
  int pl = row >> 8;
  int pg = pbase + pl;
  int c = threadIdx.x * 4;
  float4 sc = *(const float4*)(ssc + (size_t)pg * CC + c);
  float4 sh = *(const float4*)(ssh + (size_t)pg * CC + c);
  const float* hp = h + (size_t)row * 9 * CC + c;
  float4 s = {0.f, 0.f, 0.f, 0.f};
  #pragma unroll
  for (int yx = 0; yx < 9; yx++) {
    float4 v = *(const float4*)(hp + (size_t)yx * CC);
    s.x += fmaxf(fmaf(v.x, sc.x, sh.x), 0.f);
    s.y += fmaxf(fmaf(v.y, sc.y, sh.y), 0.f);
    s.z += fmaxf(fmaf(v.z, sc.z, sh.z), 0.f);
    s.w += fmaxf(fmaf(v.w, sc.w, sh.w), 0.f);
  }
  const float inv9 = 1.0f / 9.0f;
  float4 o = { s.x * inv9, s.y * inv9, s.z * inv9, s.w * inv9 };
  uint2 hh, ll;
  split_f4(o, hh, ll);
  int s_ = c >> 5, jj = (c & 31) >> 1;
  u32* op = apool + ((size_t)(pbase * 256) + row) * 1024 + s_ * 32;
  *(uint2*)(op + jj)      = hh;
  *(uint2*)(op + 16 + jj) = ll;
}

// ------------------------------------------------------------ MFMA GEMM core
// C[m][n] = sum_k A[m][k] * B[n][k] + bias[n]; A and B both pre-split planes
// staged via global_load_lds. split-bf16: acc += ah*bh + al*bh + ah*bl.
// LDS: row*32 u32, granule g (16B) at phys g^(row&7) (src pre-swizzled).
// STATS: emit per-block column sum/sumsq to partOut[mb][col][2].

template<bool STATS>
__device__ __forceinline__ void mg_body(
    const u32* __restrict__ Agl, const u32* __restrict__ Bp,
    const float* __restrict__ bias, float* __restrict__ Cmat,
    int m0, int n0, float* __restrict__ partOut, int mb)
{
  __shared__ u32 sA[2][4096];
  __shared__ u32 sB[2][4096];
  __shared__ float sr1[4][64];
  __shared__ float sr2[4][64];

  const int t = threadIdx.x;
  const int l = t & 63, wv = t >> 6;
  const int lr = l & 15, lk = l >> 4;
  const int wm = (wv >> 1) * 64, wn = (wv & 1) * 64;

  // fragment read offsets (u32) with granule XOR swizzle
  int fAh[4], fAl[4], fBh[4], fBl[4];
  #pragma unroll
  for (int i = 0; i < 4; i++) {
    int Ra = wm + i * 16 + lr;
    int Rb = wn + i * 16 + lr;
    fAh[i] = Ra * 32 + ((lk ^ (Ra & 7)) << 2);
    fAl[i] = Ra * 32 + (((4 + lk) ^ (Ra & 7)) << 2);
    fBh[i] = Rb * 32 + ((lk ^ (Rb & 7)) << 2);
    fBl[i] = Rb * 32 + (((4 + lk) ^ (Rb & 7)) << 2);
  }

  // gload addressing: wave covers rows wv*32..wv*32+31 in 4 chunks of 8 rows
  int growq[4], ggq[4];
  #pragma unroll
  for (int q = 0; q < 4; q++) {
    int rr = wv * 32 + q * 8 + (l >> 3);
    growq[q] = rr;
    ggq[q] = (((l & 7) ^ (rr & 7)) << 2);
  }
  const u32* Brow = Bp + (size_t)n0 * 1024;
  const u32* Agr  = Agl + (size_t)m0 * 1024;

  f32x4 acc[4][4];
  #pragma unroll
  for (int i = 0; i < 4; i++)
    #pragma unroll
    for (int j = 0; j < 4; j++) { f32x4 z = {0.f, 0.f, 0.f, 0.f}; acc[i][j] = z; }

  // prologue: stage slab 0
  #pragma unroll
  for (int q = 0; q < 4; q++) {
    gload16(Brow + (size_t)growq[q] * 1024 + ggq[q],
            &sB[0][(wv * 32 + q * 8) * 32]);
    gload16(Agr + (size_t)growq[q] * 1024 + ggq[q],
            &sA[0][(wv * 32 + q * 8) * 32]);
  }
  __syncthreads();

  #pragma unroll 1
  for (int it = 0; it < 32; ++it) {
    const int cur = it & 1, nxt = cur ^ 1;
    const bool pf = (it < 31);
    if (pf) {
      int so = (it + 1) << 5;
      #pragma unroll
      for (int q = 0; q < 4; q++) {
        gload16(Brow + (size_t)growq[q] * 1024 + so + ggq[q],
                &sB[nxt][(wv * 32 + q * 8) * 32]);
        gload16(Agr + (size_t)growq[q] * 1024 + so + ggq[q],
                &sA[nxt][(wv * 32 + q * 8) * 32]);
      }
    }
    bf16x8 Ah[4], Al_[4], Bh[4], Bl[4];
    #pragma unroll
    for (int i = 0; i < 4; i++) {
      Ah[i]  = *(const bf16x8*)&sA[cur][fAh[i]];
      Al_[i] = *(const bf16x8*)&sA[cur][fAl[i]];
      Bh[i]  = *(const bf16x8*)&sB[cur][fBh[i]];
      Bl[i]  = *(const bf16x8*)&sB[cur][fBl[i]];
    }
    #pragma unroll
    for (int i = 0; i < 4; i++)
      #pragma unroll
      for (int j = 0; j < 4; j++) {
        acc[i][j] = MFMA16(Ah[i],  Bh[j], acc[i][j]);
        acc[i][j] = MFMA16(Al_[i], Bh[j], acc[i][j]);
        acc[i][j] = MFMA16(Ah[i],  Bl[j], acc[i][j]);
      }
    __syncthreads();
  }

  // epilogue: D row = lk*4 + reg, col = lr [m89 layout]; optional col stats
  float st1[4], st2[4];
  #pragma unroll
  for (int j = 0; j < 4; j++) { st1[j] = 0.f; st2[j] = 0.f; }
  #pragma unroll
  for (int j = 0; j < 4; j++) {
    int ocol = n0 + wn + j * 16 + lr;
    float bj = bias[ocol];
    #pragma unroll
    for (int i = 0; i < 4; i++) {
      int orow = m0 + wm + i * 16 + lk * 4;
      float* cp = Cmat + (size_t)orow * CC + ocol;
      #pragma unroll
      for (int reg = 0; reg < 4; reg++) {
        float v = acc[i][j][reg] + bj;
        cp[(size_t)reg * CC] = v;
        if (STATS) { st1[j] += v; st2[j] = fmaf(v, v, st2[j]); }
      }
    }
  }
  if (STATS) {
    #pragma unroll
    for (int j = 0; j < 4; j++) {
      st1[j] += __shfl_xor(st1[j], 16, 64);
      st1[j] += __shfl_xor(st1[j], 32, 64);
      st2[j] += __shfl_xor(st2[j], 16, 64);
      st2[j] += __shfl_xor(st2[j], 32, 64);
    }
    if (lk == 0) {
      #pragma unroll
      for (int j = 0; j < 4; j++) {
        sr1[wv][j * 16 + lr] = st1[j];
        sr2[wv][j * 16 + lr] = st2[j];
      }
    }
    __syncthreads();
    if (t < 128) {
      int ch = t >> 6, c6 = t & 63;
      float a1 = sr1[ch][c6] + sr1[ch + 2][c6];
      float a2 = sr2[ch][c6] + sr2[ch + 2][c6];
      float2 o = { a1, a2 };
      *(float2*)(partOut + ((size_t)mb * CC + n0 + t) * 2) = o;
    }
  }
}

// conv wrapper with grouped block swizzle (GROUP m-tiles x 8 n-tiles per group)
#define SWZ_G 64

template<bool STATS>
__global__ __launch_bounds__(256, 2)
void k_mg(const u32* __restrict__ A, const u32* __restrict__ Bp,
          const float* __restrict__ bias, float* __restrict__ Cmat,
          int mtiles, float* __restrict__ partOut)
{
  int id = blockIdx.y * gridDim.x + blockIdx.x;
  int g = id / (SWZ_G * 8);
  int rem = id - g * (SWZ_G * 8);
  int gsz = mtiles - g * SWZ_G; if (gsz > SWZ_G) gsz = SWZ_G;
  int mt = g * SWZ_G + rem % gsz;
  int nt = rem / gsz;
  mg_body<STATS>(A, Bp, bias, Cmat, mt * 128, nt * 128, partOut, mt);
}

__global__ __launch_bounds__(256, 2)
void k_heads(const u32* __restrict__ ctxp, const u32* __restrict__ wplh,
             const float* __restrict__ lb, float* __restrict__ out)
{
  int p, w;
  head_entry(blockIdx.y, &p, &w);
  mg_body<false>(ctxp + (size_t)p * BB * 1024,
                 wplh + (size_t)w * 1048576,
                 lb + (size_t)w * CC,
                 out + (size_t)blockIdx.y * BB * CC,
                 (blockIdx.x >> 3) * 128, (blockIdx.x & 7) * 128,
                 nullptr, 0);
}

// ---------------------------------------------------------------- launch

extern "C" void kernel_launch(void* const* d_in, const int* in_sizes, int n_in,
                              void* d_out, int out_size, void* d_ws, size_t ws_size,
                              hipStream_t stream)
{
  const float* x   = (const float*)d_in[0];
  const float* bng = (const float*)d_in[1];
  const float* bnb = (const float*)d_in[2];
  const float* cw  = (const float*)d_in[3];
  const float* cb  = (const float*)d_in[4];
  const float* lw  = (const float*)d_in[5];
  const float* lb  = (const float*)d_in[6];
  float* out = (float*)d_out;
  float* ws  = (float*)d_ws;

  const size_t W = ws_size / 4;           // 4-byte words
  const size_t SZ_WPL  = 15ull * 1048576;
  const size_t SZ_XT   = 256ull * 49 * 1024;
  const size_t SZ_PS   = 6400ull * 1024;  // pooled split (u32)
  const size_t SZ_CTX  = 6400ull * 1024;
  const size_t SZ_CTXP = 6400ull * 1024;
  const size_t SZ_XS   = 50176;
  const size_t SZ_SS   = 25ull * 1024;

  auto need = [&](int pc, bool xt) -> size_t {
    return SZ_WPL + (xt ? SZ_XT : 0) + 2ull * pc * 2304 * 1024
         + SZ_PS + SZ_CTX + SZ_CTXP + 2 * SZ_XS + 2 * SZ_SS
         + (size_t)pc * 18 * 1024 * 2;
  };
  int PC; bool useXT;
  if      (W >= need(25, true))  { PC = 25; useXT = true;  }
  else if (W >= need(5, true))   { PC = 5;  useXT = true;  }
  else if (W >= need(1, true))   { PC = 1;  useXT = true;  }
  else                           { PC = 1;  useXT = false; }

  u32*   wpl    = (u32*)ws;
  float* xtg    = (float*)(wpl + SZ_WPL);
  float* bufF   = xtg + (useXT ? SZ_XT : 0);
  u32*   bufS   = (u32*)(bufF + (size_t)PC * 2304 * 1024);
  u32*   pooledS= bufS + (size_t)PC * 2304 * 1024;
  float* ctx    = (float*)(pooledS + SZ_PS);
  u32*   ctxp   = (u32*)(ctx + SZ_CTX);
  float* xs1    = (float*)(ctxp + SZ_CTXP);
  float* xs2    = xs1 + SZ_XS;
  float* ssc    = xs2 + SZ_XS;
  float* ssh    = ssc + SZ_SS;
  float* part   = ssh + SZ_SS;

  // pre-split all 15 weight matrices into gload layout
  k_wsplit<<<(3 * 1048576) / 256, 256, 0, stream>>>(cw, wpl, 3 * 1048576);
  k_wsplit<<<(12 * 1048576) / 256, 256, 0, stream>>>(lw, wpl + 3ull * 1048576,
                                                     12 * 1048576);
  if (useXT) k_transpose<<<dim3(256, 8), 256, 0, stream>>>(x, xtg);
  k_xsums<<<196, 256, 0, stream>>>(x, xs1, xs2);
  k_stats1<<<dim3(25, 4), 256, 0, stream>>>(xs1, xs2, bng, bnb, ssc, ssh);

  for (int pbase = 0; pbase < NP; pbase += PC) {
    const int rows = PC * 2304;
    const int mtiles = PC * 18;
    const dim3 gconv(mtiles, 8);
    // A1: BN1+relu+split from xt (or x fallback) -> bufS
    if (useXT)
      k_absplit<1><<<rows / 8, 256, 0, stream>>>(xtg, ssc, ssh, bufS, pbase);
    else
      k_absplit<2><<<rows / 8, 256, 0, stream>>>(x, ssc, ssh, bufS, pbase);
    // conv1: bufS -> bufF, col stats -> part
    k_mg<true><<<gconv, 256, 0, stream>>>(bufS, wpl, cb, bufF, mtiles, part);
    k_statsfin<<<dim3(PC, 4), 256, 0, stream>>>(part, bng + CC, bnb + CC, ssc, ssh, pbase);
    // A2: BN2+relu+split from bufF -> bufS
    k_absplit<0><<<rows / 8, 256, 0, stream>>>(bufF, ssc, ssh, bufS, pbase);
    // conv2: bufS -> bufF, stats -> part
    k_mg<true><<<gconv, 256, 0, stream>>>(bufS, wpl + 1ull * 1048576, cb + CC,
                                          bufF, mtiles, part);
    k_statsfin<<<dim3(PC, 4), 256, 0, stream>>>(part, bng + 2 * CC, bnb + 2 * CC, ssc, ssh, pbase);
    // BN3+relu+pool, split output -> pooledS slice
    k_pool<<<PC * 256, 256, 0, stream>>>(bufF, ssc, ssh, pooledS, pbase);
  }

  // conv3 over all pooled rows (gload A) -> ctx
  k_mg<false><<<dim3(50, 8), 256, 0, stream>>>(pooledS, wpl + 2ull * 1048576,
                                               cb + 2 * CC, ctx, 50, nullptr);
  // ctx -> split, then heads (pure gload)
  k_wsplit<<<(6400 * 1024) / 256, 256, 0, stream>>>(ctx, ctxp, 6400 * 1024);
  k_heads<<<dim3(16, 120), 256, 0, stream>>>(ctxp, wpl + 3ull * 1048576, lb, out);
}

// Round 12
// 1179.495 us; speedup vs baseline: 1.5871x; 1.2660x over previous
//
#include <hip/hip_runtime.h>
#include <hip/hip_bf16.h>
#include <stdint.h>

#define BB 256
#define CC 1024
#define NP 25
#define EPS 1e-5f

typedef __attribute__((ext_vector_type(8))) short bf16x8;
typedef __attribute__((ext_vector_type(4))) float f32x4;
typedef unsigned int u32;

#define MFMA16(A, B, C) __builtin_amdgcn_mfma_f32_16x16x32_bf16(A, B, C, 0, 0, 0)

// async global->LDS, 16B per lane; LDS dest = wave-uniform base + lane*16
__device__ __forceinline__ void gload16(const u32* g, u32* l)
{
  __builtin_amdgcn_global_load_lds(
      (const __attribute__((address_space(1))) u32*)g,
      (__attribute__((address_space(3))) u32*)l, 16, 0, 0);
}

// ---------------------------------------------------------------- utils

__device__ __forceinline__ void head_entry(int j, int* pp, int* ww)
{
  int cnt = 0;
  for (int y1 = 0; y1 < 5; y1++)
    for (int x1 = 0; x1 < 5; x1++) {
      int p = y1 * 5 + x1;
      int y2 = y1 + 2, x2 = x1 + 2;
      if (y2 == 2 || y2 == 3)
        for (int s = 0; s < 3; s++) { if (y2 + s + 1 > 6) break; if (cnt == j) { *pp = p; *ww = 0 + s; return; } cnt++; }
      if (y1 == 3 || y1 == 4)
        for (int s = 0; s < 3; s++) { if (y1 - (s + 1) < 0) break; if (cnt == j) { *pp = p; *ww = 3 + s; return; } cnt++; }
      if (x2 == 2 || x2 == 3)
        for (int s = 0; s < 3; s++) { if (x2 + s + 1 > 6) break; if (cnt == j) { *pp = p; *ww = 6 + s; return; } cnt++; }
      if (x1 == 3 || x1 == 4)
        for (int s = 0; s < 3; s++) { if (x1 - (s + 1) < 0) break; if (cnt == j) { *pp = p; *ww = 9 + s; return; } cnt++; }
    }
}

// split fp32 -> hi bf16 (truncate) + lo bf16 (remainder); pack pairs into u32
__device__ __forceinline__ void split_f4(float4 f, uint2& h, uint2& l)
{
  u32 ux = __float_as_uint(f.x), uy = __float_as_uint(f.y);
  u32 uz = __float_as_uint(f.z), uw = __float_as_uint(f.w);
  h.x = (ux >> 16) | (uy & 0xFFFF0000u);
  h.y = (uz >> 16) | (uw & 0xFFFF0000u);
  float lx = f.x - __uint_as_float(ux & 0xFFFF0000u);
  float ly = f.y - __uint_as_float(uy & 0xFFFF0000u);
  float lz = f.z - __uint_as_float(uz & 0xFFFF0000u);
  float lw = f.w - __uint_as_float(uw & 0xFFFF0000u);
  l.x = (__float_as_uint(lx) >> 16) | (__float_as_uint(ly) & 0xFFFF0000u);
  l.y = (__float_as_uint(lz) >> 16) | (__float_as_uint(lw) & 0xFFFF0000u);
}

// round-to-nearest-even bf16 (keep high 16 bits)
__device__ __forceinline__ u32 rne_hi(u32 x)
{
  return (x + 0x7FFFu + ((x >> 16) & 1u)) & 0xFFFF0000u;
}

// ------------------------------------------------- layer-1 stats from x

__global__ void k_xsums(const float* __restrict__ x, float* __restrict__ xs1,
                        float* __restrict__ xs2)
{
  int pos = blockIdx.x * 256 + threadIdx.x;   // < 50176
  float s1 = 0.f, s2 = 0.f;
  for (int b = 0; b < BB; b++) {
    float v = x[(size_t)b * 50176 + pos];
    s1 += v; s2 = fmaf(v, v, s2);
  }
  xs1[pos] = s1; xs2[pos] = s2;
}

__global__ void k_stats1(const float* __restrict__ xs1, const float* __restrict__ xs2,
                         const float* __restrict__ gam, const float* __restrict__ bet,
                         float* __restrict__ ssc, float* __restrict__ ssh)
{
  int p = blockIdx.x;
  int c = blockIdx.y * 256 + threadIdx.x;
  int y1 = p / 5, x1 = p % 5;
  float s1 = 0.f, s2 = 0.f;
  for (int dy = 0; dy < 3; dy++)
    for (int dx = 0; dx < 3; dx++) {
      int pos = c * 49 + (y1 + dy) * 7 + (x1 + dx);
      s1 += xs1[pos]; s2 += xs2[pos];
    }
  const float inv = 1.0f / 2304.0f;
  float mean = s1 * inv;
  float var  = s2 * inv - mean * mean;
  float rs   = rsqrtf(var + EPS);
  float sc   = rs * gam[c];
  ssc[(size_t)p * CC + c] = sc;
  ssh[(size_t)p * CC + c] = bet[c] - mean * sc;
}

// ------------------------- one-time x transpose: x[b][c][yx] -> xt[b][yx][c]

__global__ void k_transpose(const float* __restrict__ x, float* __restrict__ xt)
{
  __shared__ float tile[128][51];
  int b = blockIdx.x, cg = blockIdx.y;
  const float* src = x + (size_t)b * 50176 + (size_t)cg * 128 * 49;
  for (int idx = threadIdx.x; idx < 6272; idx += 256)
    tile[idx / 49][idx % 49] = src[idx];
  __syncthreads();
  float* dst = xt + (size_t)b * 49 * 1024 + cg * 128;
  for (int pp = 0; pp < 50; pp += 2) {
    int p = pp + (threadIdx.x >> 7);
    int i = threadIdx.x & 127;
    if (p < 49) dst[(size_t)p * 1024 + i] = tile[i][p];
  }
}

// ---------- head weights / ctx pre-split (trunc hi+lo, 1024-u32 rows)
// row = 1024 u32: [slab 0..31][ 16 u32 hi pairs | 16 u32 lo pairs ]

__global__ void k_wsplit(const float* __restrict__ w, u32* __restrict__ dst, int total)
{
  int g = blockIdx.x * 256 + threadIdx.x;
  if (g >= total) return;
  int row = g >> 10;
  int rem = g & 1023;
  int slab = rem >> 5, j = rem & 31;
  int lo = j >> 4, jj = j & 15;
  const float* src = w + ((size_t)row << 10) + slab * 32 + 2 * jj;
  float f0 = src[0], f1 = src[1];
  u32 u0 = __float_as_uint(f0), u1 = __float_as_uint(f1);
  u32 v;
  if (lo == 0) {
    v = (u0 >> 16) | (u1 & 0xFFFF0000u);
  } else {
    float l0 = f0 - __uint_as_float(u0 & 0xFFFF0000u);
    float l1 = f1 - __uint_as_float(u1 & 0xFFFF0000u);
    v = (__float_as_uint(l0) >> 16) | (__float_as_uint(l1) & 0xFFFF0000u);
  }
  dst[g] = v;
}

// ---------- conv weights: RNE hi-only layout (512-u32 rows, slab = 16 u32)

__global__ void k_wsplit_rn(const float* __restrict__ w, u32* __restrict__ dst, int total)
{
  int g = blockIdx.x * 256 + threadIdx.x;
  if (g >= total) return;
  int row = g >> 9;
  int idx = g & 511;
  const float* src = w + ((size_t)row << 10) + 2 * idx;
  u32 u0 = __float_as_uint(src[0]);
  u32 u1 = __float_as_uint(src[1]);
  dst[g] = (rne_hi(u0) >> 16) | rne_hi(u1);
}

// ------------- A-operand affine+relu+split into gload layout (trunc hi+lo)
// MODE 0: src = fp32 rows (conv2 A); MODE 1: src = xt, patch row-map (conv1 A);
// MODE 2: src = x, strided reads (no-xt fallback).

template<int MODE>
__global__ void k_absplit(const float* __restrict__ src,
                          const float* __restrict__ ssc, const float* __restrict__ ssh,
                          u32* __restrict__ dst, int pbase)
{
  int r = blockIdx.x * 8 + (threadIdx.x >> 5);   // local row
  int slab = threadIdx.x & 31;
  int pg;
  const float* sp = nullptr;
  const float* xb = nullptr;
  if (MODE == 0) {
    pg = pbase + r / 2304;
    sp = src + (size_t)r * 1024 + slab * 32;
  } else {
    int pl = r / 2304, q = r - pl * 2304;
    pg = pbase + pl;
    int b = q / 9, yx = q - b * 9;
    int pos = (pg / 5 + yx / 3) * 7 + (pg % 5) + (yx % 3);
    if (MODE == 1) sp = src + ((size_t)b * 49 + pos) * 1024 + slab * 32;
    else           xb = src + (size_t)b * 50176 + (size_t)slab * 32 * 49 + pos;
  }
  const float* scp = ssc + (size_t)pg * CC + slab * 32;
  const float* shp = ssh + (size_t)pg * CC + slab * 32;
  u32 hi[16], lo[16];
  #pragma unroll
  for (int j = 0; j < 8; j++) {
    float4 f;
    if (MODE == 2) {
      f.x = xb[(size_t)(4 * j + 0) * 49]; f.y = xb[(size_t)(4 * j + 1) * 49];
      f.z = xb[(size_t)(4 * j + 2) * 49]; f.w = xb[(size_t)(4 * j + 3) * 49];
    } else {
      f = *(const float4*)(sp + 4 * j);
    }
    float4 s = *(const float4*)(scp + 4 * j);
    float4 h = *(const float4*)(shp + 4 * j);
    f.x = fmaxf(fmaf(f.x, s.x, h.x), 0.f);
    f.y = fmaxf(fmaf(f.y, s.y, h.y), 0.f);
    f.z = fmaxf(fmaf(f.z, s.z, h.z), 0.f);
    f.w = fmaxf(fmaf(f.w, s.w, h.w), 0.f);
    uint2 hh, ll;
    split_f4(f, hh, ll);
    hi[2 * j] = hh.x; hi[2 * j + 1] = hh.y;
    lo[2 * j] = ll.x; lo[2 * j + 1] = ll.y;
  }
  u32* op = dst + (size_t)r * 1024 + slab * 32;
  *(uint4*)(op + 0)  = make_uint4(hi[0], hi[1], hi[2], hi[3]);
  *(uint4*)(op + 4)  = make_uint4(hi[4], hi[5], hi[6], hi[7]);
  *(uint4*)(op + 8)  = make_uint4(hi[8], hi[9], hi[10], hi[11]);
  *(uint4*)(op + 12) = make_uint4(hi[12], hi[13], hi[14], hi[15]);
  *(uint4*)(op + 16) = make_uint4(lo[0], lo[1], lo[2], lo[3]);
  *(uint4*)(op + 20) = make_uint4(lo[4], lo[5], lo[6], lo[7]);
  *(uint4*)(op + 24) = make_uint4(lo[8], lo[9], lo[10], lo[11]);
  *(uint4*)(op + 28) = make_uint4(lo[12], lo[13], lo[14], lo[15]);
}

// ------------------- finalize BN stats from per-mblock partials (18/patch)

__global__ void k_statsfin(const float* __restrict__ part, const float* __restrict__ gam,
                           const float* __restrict__ bet, float* __restrict__ ssc,
                           float* __restrict__ ssh, int pbase)
{
  int pl = blockIdx.x;
  int c  = blockIdx.y * 256 + threadIdx.x;
  float s1 = 0.f, s2 = 0.f;
  for (int mb = 0; mb < 18; mb++) {
    const float* pp = part + ((size_t)(pl * 18 + mb) * CC + c) * 2;
    s1 += pp[0]; s2 += pp[1];
  }
  const float inv = 1.0f / 2304.0f;
  float mean = s1 * inv;
  float var  = s2 * inv - mean * mean;
  float rs   = rsqrtf(var + EPS);
  float sc   = rs * gam[c];
  int pg = pbase + pl;
  ssc[(size_t)pg * CC + c] = sc;
  ssh[(size_t)pg * CC + c] = bet[c] - mean * sc;
}

// ---- BN3 affine+relu + 3x3 mean pooling, output in split gload layout

__global__ void k_pool(const float* __restrict__ h, const float* __restrict__ ssc,
                       const float* __restrict__ ssh, u32* __restrict__ apool, int pbase)
{
  int row = blockIdx.x;                 // local: pl*256 + b
  int pl = row >> 8;
  int pg = pbase + pl;
  int c = threadIdx.x * 4;
  float4 sc = *(const float4*)(ssc + (size_t)pg * CC + c);
  float4 sh = *(const float4*)(ssh + (size_t)pg * CC + c);
  const float* hp = h + (size_t)row * 9 * CC + c;
  float4 s = {0.f, 0.f, 0.f, 0.f};
  #pragma unroll
  for (int yx = 0; yx < 9; yx++) {
    float4 v = *(const float4*)(hp + (size_t)yx * CC);
    s.x += fmaxf(fmaf(v.x, sc.x, sh.x), 0.f);
    s.y += fmaxf(fmaf(v.y, sc.y, sh.y), 0.f);
    s.z += fmaxf(fmaf(v.z, sc.z, sh.z), 0.f);
    s.w += fmaxf(fmaf(v.w, sc.w, sh.w), 0.f);
  }
  const float inv9 = 1.0f / 9.0f;
  float4 o = { s.x * inv9, s.y * inv9, s.z * inv9, s.w * inv9 };
  uint2 hh, ll;
  split_f4(o, hh, ll);
  int s_ = c >> 5, jj = (c & 31) >> 1;
  u32* op = apool + ((size_t)(pbase * 256) + row) * 1024 + s_ * 32;
  *(uint2*)(op + jj)      = hh;
  *(uint2*)(op + 16 + jj) = ll;
}

// ------------------------------------------------------------ MFMA GEMM core
// C[m][n] = sum_k A[m][k] * B[n][k] + bias[n]; A pre-split hi/lo, staged via
// global_load_lds. BP=2 (heads): B 2-plane trunc, 3 products (a exact to 2^-16).
// BP=1 (convs):  B hi-only RNE (512-u32 rows), 2 products (ah+al)*bh.
// LDS: A row 32 u32, granule g^(row&7); B(BP=1) row 16 u32, granule g^((row>>1)&3)
//   (row>>1 spreads same-bank-parity rows over all 4 granule slots -> 2-way max).
// STATS: per-block column sum/sumsq -> partOut[mb][col][2].

template<int BP, bool STATS>
__device__ __forceinline__ void mg_body(
    const u32* __restrict__ Agl, const u32* __restrict__ Bp,
    const float* __restrict__ bias, float* __restrict__ Cmat,
    int m0, int n0, float* __restrict__ partOut, int mb)
{
  constexpr int BRS  = (BP == 1) ? 512 : 1024;   // B row stride (u32)
  constexpr int BLDS = (BP == 1) ? 2048 : 4096;  // B LDS u32 per buffer
  __shared__ u32 sA[2][4096];
  __shared__ u32 sB[2][BLDS];
  __shared__ float sr1[4][64];
  __shared__ float sr2[4][64];

  const int t = threadIdx.x;
  const int l = t & 63, wv = t >> 6;
  const int lr = l & 15, lk = l >> 4;
  const int wm = (wv >> 1) * 64, wn = (wv & 1) * 64;

  // fragment read offsets (u32) with granule XOR swizzle
  int fAh[4], fAl[4], fBh[4], fBl[4];
  #pragma unroll
  for (int i = 0; i < 4; i++) {
    int Ra = wm + i * 16 + lr;
    int Rb = wn + i * 16 + lr;
    fAh[i] = Ra * 32 + ((lk ^ (Ra & 7)) << 2);
    fAl[i] = Ra * 32 + (((4 + lk) ^ (Ra & 7)) << 2);
    if (BP == 1) {
      fBh[i] = Rb * 16 + ((lk ^ ((Rb >> 1) & 3)) << 2);
      fBl[i] = 0;
    } else {
      fBh[i] = Rb * 32 + ((lk ^ (Rb & 7)) << 2);
      fBl[i] = Rb * 32 + (((4 + lk) ^ (Rb & 7)) << 2);
    }
  }

  // A gload: 4 chunks of 8 rows (32-u32 rows)
  int growq[4], ggq[4];
  #pragma unroll
  for (int q = 0; q < 4; q++) {
    int rr = wv * 32 + q * 8 + (l >> 3);
    growq[q] = rr;
    ggq[q] = (((l & 7) ^ (rr & 7)) << 2);
  }
  // B gload: BP=1 -> 2 chunks of 16 rows (16-u32 rows); BP=2 -> as A
  int brow[4], bg[4];
  constexpr int NBQ = (BP == 1) ? 2 : 4;
  #pragma unroll
  for (int q = 0; q < NBQ; q++) {
    if (BP == 1) {
      int rr = wv * 32 + q * 16 + (l >> 2);
      brow[q] = rr;
      bg[q] = (((l & 3) ^ ((rr >> 1) & 3)) << 2);
    } else {
      brow[q] = growq[q];
      bg[q] = ggq[q];
    }
  }
  const u32* Brow = Bp + (size_t)n0 * BRS;
  const u32* Agr  = Agl + (size_t)m0 * 1024;

  f32x4 acc[4][4];
  #pragma unroll
  for (int i = 0; i < 4; i++)
    #pragma unroll
    for (int j = 0; j < 4; j++) { f32x4 z = {0.f, 0.f, 0.f, 0.f}; acc[i][j] = z; }

  // prologue: stage slab 0
  #pragma unroll
  for (int q = 0; q < NBQ; q++)
    gload16(Brow + (size_t)brow[q] * BRS + bg[q],
            &sB[0][(BP == 1) ? (wv * 32 + q * 16) * 16 : (wv * 32 + q * 8) * 32]);
  #pragma unroll
  for (int q = 0; q < 4; q++)
    gload16(Agr + (size_t)growq[q] * 1024 + ggq[q],
            &sA[0][(wv * 32 + q * 8) * 32]);
  __syncthreads();

  #pragma unroll 1
  for (int it = 0; it < 32; ++it) {
    const int cur = it & 1, nxt = cur ^ 1;
    const bool pf = (it < 31);
    if (pf) {
      const int soA = (it + 1) << 5;
      const int soB = (BP == 1) ? ((it + 1) << 4) : soA;
      #pragma unroll
      for (int q = 0; q < NBQ; q++)
        gload16(Brow + (size_t)brow[q] * BRS + soB + bg[q],
                &sB[nxt][(BP == 1) ? (wv * 32 + q * 16) * 16 : (wv * 32 + q * 8) * 32]);
      #pragma unroll
      for (int q = 0; q < 4; q++)
        gload16(Agr + (size_t)growq[q] * 1024 + soA + ggq[q],
                &sA[nxt][(wv * 32 + q * 8) * 32]);
    }
    bf16x8 Ah[4], Al_[4], Bh[4], Bl[4];
    #pragma unroll
    for (int i = 0; i < 4; i++) {
      Ah[i]  = *(const bf16x8*)&sA[cur][fAh[i]];
      Al_[i] = *(const bf16x8*)&sA[cur][fAl[i]];
      Bh[i]  = *(const bf16x8*)&sB[cur][fBh[i]];
      if (BP == 2) Bl[i] = *(const bf16x8*)&sB[cur][fBl[i]];
    }
    #pragma unroll
    for (int i = 0; i < 4; i++)
      #pragma unroll
      for (int j = 0; j < 4; j++) {
        acc[i][j] = MFMA16(Ah[i],  Bh[j], acc[i][j]);
        acc[i][j] = MFMA16(Al_[i], Bh[j], acc[i][j]);
        if (BP == 2) acc[i][j] = MFMA16(Ah[i], Bl[j], acc[i][j]);
      }
    __syncthreads();
  }

  // epilogue: D row = lk*4 + reg, col = lr [m89 layout]; optional col stats
  float st1[4], st2[4];
  #pragma unroll
  for (int j = 0; j < 4; j++) { st1[j] = 0.f; st2[j] = 0.f; }
  #pragma unroll
  for (int j = 0; j < 4; j++) {
    int ocol = n0 + wn + j * 16 + lr;
    float bj = bias[ocol];
    #pragma unroll
    for (int i = 0; i < 4; i++) {
      int orow = m0 + wm + i * 16 + lk * 4;
      float* cp = Cmat + (size_t)orow * CC + ocol;
      #pragma unroll
      for (int reg = 0; reg < 4; reg++) {
        float v = acc[i][j][reg] + bj;
        cp[(size_t)reg * CC] = v;
        if (STATS) { st1[j] += v; st2[j] = fmaf(v, v, st2[j]); }
      }
    }
  }
  if (STATS) {
    #pragma unroll
    for (int j = 0; j < 4; j++) {
      st1[j] += __shfl_xor(st1[j], 16, 64);
      st1[j] += __shfl_xor(st1[j], 32, 64);
      st2[j] += __shfl_xor(st2[j], 16, 64);
      st2[j] += __shfl_xor(st2[j], 32, 64);
    }
    if (lk == 0) {
      #pragma unroll
      for (int j = 0; j < 4; j++) {
        sr1[wv][j * 16 + lr] = st1[j];
        sr2[wv][j * 16 + lr] = st2[j];
      }
    }
    __syncthreads();
    if (t < 128) {
      int ch = t >> 6, c6 = t & 63;
      float a1 = sr1[ch][c6] + sr1[ch + 2][c6];
      float a2 = sr2[ch][c6] + sr2[ch + 2][c6];
      float2 o = { a1, a2 };
      *(float2*)(partOut + ((size_t)mb * CC + n0 + t) * 2) = o;
    }
  }
}

// conv wrapper with grouped block swizzle (GROUP m-tiles x 8 n-tiles per group)
#define SWZ_G 64

template<bool STATS>
__global__ __launch_bounds__(256, 2)
void k_mg(const u32* __restrict__ A, const u32* __restrict__ Bp,
          const float* __restrict__ bias, float* __restrict__ Cmat,
          int mtiles, float* __restrict__ partOut)
{
  int id = blockIdx.y * gridDim.x + blockIdx.x;
  int g = id / (SWZ_G * 8);
  int rem = id - g * (SWZ_G * 8);
  int gsz = mtiles - g * SWZ_G; if (gsz > SWZ_G) gsz = SWZ_G;
  int mt = g * SWZ_G + rem % gsz;
  int nt = rem / gsz;
  mg_body<1, STATS>(A, Bp, bias, Cmat, mt * 128, nt * 128, partOut, mt);
}

__global__ __launch_bounds__(256, 2)
void k_heads(const u32* __restrict__ ctxp, const u32* __restrict__ wplh,
             const float* __restrict__ lb, float* __restrict__ out)
{
  int p, w;
  head_entry(blockIdx.y, &p, &w);
  mg_body<2, false>(ctxp + (size_t)p * BB * 1024,
                    wplh + (size_t)w * 1048576,
                    lb + (size_t)w * CC,
                    out + (size_t)blockIdx.y * BB * CC,
                    (blockIdx.x >> 3) * 128, (blockIdx.x & 7) * 128,
                    nullptr, 0);
}

// ---------------------------------------------------------------- launch

extern "C" void kernel_launch(void* const* d_in, const int* in_sizes, int n_in,
                              void* d_out, int out_size, void* d_ws, size_t ws_size,
                              hipStream_t stream)
{
  const float* x   = (const float*)d_in[0];
  const float* bng = (const float*)d_in[1];
  const float* bnb = (const float*)d_in[2];
  const float* cw  = (const float*)d_in[3];
  const float* cb  = (const float*)d_in[4];
  const float* lw  = (const float*)d_in[5];
  const float* lb  = (const float*)d_in[6];
  float* out = (float*)d_out;
  float* ws  = (float*)d_ws;

  const size_t W = ws_size / 4;           // 4-byte words
  const size_t SZ_WHI  = 3ull * 524288;   // conv weights, RNE hi-only
  const size_t SZ_WPL  = 12ull * 1048576; // head weights, trunc hi+lo
  const size_t SZ_XT   = 256ull * 49 * 1024;
  const size_t SZ_PS   = 6400ull * 1024;  // pooled split (u32)
  const size_t SZ_CTX  = 6400ull * 1024;
  const size_t SZ_CTXP = 6400ull * 1024;
  const size_t SZ_XS   = 50176;
  const size_t SZ_SS   = 25ull * 1024;

  auto need = [&](int pc, bool xt) -> size_t {
    return SZ_WHI + SZ_WPL + (xt ? SZ_XT : 0) + 2ull * pc * 2304 * 1024
         + SZ_PS + SZ_CTX + SZ_CTXP + 2 * SZ_XS + 2 * SZ_SS
         + (size_t)pc * 18 * 1024 * 2;
  };
  int PC; bool useXT;
  if      (W >= need(25, true))  { PC = 25; useXT = true;  }
  else if (W >= need(5, true))   { PC = 5;  useXT = true;  }
  else if (W >= need(1, true))   { PC = 1;  useXT = true;  }
  else                           { PC = 1;  useXT = false; }

  u32*   whi    = (u32*)ws;
  u32*   wpl    = whi + SZ_WHI;
  float* xtg    = (float*)(wpl + SZ_WPL);
  float* bufF   = xtg + (useXT ? SZ_XT : 0);
  u32*   bufS   = (u32*)(bufF + (size_t)PC * 2304 * 1024);
  u32*   pooledS= bufS + (size_t)PC * 2304 * 1024;
  float* ctx    = (float*)(pooledS + SZ_PS);
  u32*   ctxp   = (u32*)(ctx + SZ_CTX);
  float* xs1    = (float*)(ctxp + SZ_CTXP);
  float* xs2    = xs1 + SZ_XS;
  float* ssc    = xs2 + SZ_XS;
  float* ssh    = ssc + SZ_SS;
  float* part   = ssh + SZ_SS;

  // weight pre-split: conv (RNE hi-only) + heads (trunc hi+lo)
  k_wsplit_rn<<<(int)(SZ_WHI / 256), 256, 0, stream>>>(cw, whi, (int)SZ_WHI);
  k_wsplit<<<(12 * 1048576) / 256, 256, 0, stream>>>(lw, wpl, 12 * 1048576);
  if (useXT) k_transpose<<<dim3(256, 8), 256, 0, stream>>>(x, xtg);
  k_xsums<<<196, 256, 0, stream>>>(x, xs1, xs2);
  k_stats1<<<dim3(25, 4), 256, 0, stream>>>(xs1, xs2, bng, bnb, ssc, ssh);

  for (int pbase = 0; pbase < NP; pbase += PC) {
    const int rows = PC * 2304;
    const int mtiles = PC * 18;
    const dim3 gconv(mtiles, 8);
    // A1: BN1+relu+split from xt (or x fallback) -> bufS
    if (useXT)
      k_absplit<1><<<rows / 8, 256, 0, stream>>>(xtg, ssc, ssh, bufS, pbase);
    else
      k_absplit<2><<<rows / 8, 256, 0, stream>>>(x, ssc, ssh, bufS, pbase);
    // conv1: bufS -> bufF, col stats -> part
    k_mg<true><<<gconv, 256, 0, stream>>>(bufS, whi, cb, bufF, mtiles, part);
    k_statsfin<<<dim3(PC, 4), 256, 0, stream>>>(part, bng + CC, bnb + CC, ssc, ssh, pbase);
    // A2: BN2+relu+split from bufF -> bufS
    k_absplit<0><<<rows / 8, 256, 0, stream>>>(bufF, ssc, ssh, bufS, pbase);
    // conv2: bufS -> bufF, stats -> part
    k_mg<true><<<gconv, 256, 0, stream>>>(bufS, whi + 524288, cb + CC,
                                          bufF, mtiles, part);
    k_statsfin<<<dim3(PC, 4), 256, 0, stream>>>(part, bng + 2 * CC, bnb + 2 * CC, ssc, ssh, pbase);
    // BN3+relu+pool, split output -> pooledS slice
    k_pool<<<PC * 256, 256, 0, stream>>>(bufF, ssc, ssh, pooledS, pbase);
  }

  // conv3 over all pooled rows -> ctx
  k_mg<false><<<dim3(50, 8), 256, 0, stream>>>(pooledS, whi + 2 * 524288,
                                               cb + 2 * CC, ctx, 50, nullptr);
  // ctx -> split (trunc hi+lo), then heads (3-product path)
  k_wsplit<<<(6400 * 1024) / 256, 256, 0, stream>>>(ctx, ctxp, 6400 * 1024);
  k_heads<<<dim3(16, 120), 256, 0, stream>>>(ctxp, wpl, lb, out);
}